// Round 1
// baseline (276.868 us; speedup 1.0000x reference)
//
#include <hip/hip_runtime.h>

typedef unsigned short u16;
typedef unsigned int u32;
typedef __attribute__((ext_vector_type(8))) short bf16x8;
typedef __attribute__((ext_vector_type(4))) float f32x4;

__device__ __forceinline__ u16 f2b(float f) {
    union { float f; u32 u; } v; v.f = f;
    return (u16)((v.u + 0x7FFF + ((v.u >> 16) & 1)) >> 16);  // RNE
}

__device__ __forceinline__ void glds16(const u16* g, u16* l) {
    __builtin_amdgcn_global_load_lds(
        (const __attribute__((address_space(1))) void*)g,
        (__attribute__((address_space(3))) void*)l, 16, 0, 0);
}

// ---------------------------------------------------------------------------
// fp32 -> bf16 flat casts for Q, K, V (grid.z selects input). n4 = 1048576.
// ---------------------------------------------------------------------------
__global__ __launch_bounds__(256) void cast3(
    const float* __restrict__ Q, const float* __restrict__ K,
    const float* __restrict__ V,
    u16* __restrict__ Qb, u16* __restrict__ Kb, u16* __restrict__ Vb)
{
    const float* in = (blockIdx.z == 0) ? Q : (blockIdx.z == 1) ? K : V;
    u16* out = (blockIdx.z == 0) ? Qb : (blockIdx.z == 1) ? Kb : Vb;
    const int n4 = 1048576;
    const int stride = gridDim.x * 256;
    for (int i = blockIdx.x * 256 + threadIdx.x; i < n4; i += stride) {
        float4 v = ((const float4*)in)[i];
        ushort4 o;
        o.x = f2b(v.x); o.y = f2b(v.y); o.z = f2b(v.z); o.w = f2b(v.w);
        ((ushort4*)out)[i] = o;
    }
}

// ---------------------------------------------------------------------------
// Per-head weight transpose-cast: fp32 [16][1024][64] -> bf16 [16][64][1024].
// grid (16, 1, 48): z>>4 selects Wq/Wk/Wv, z&15 = head.
// ---------------------------------------------------------------------------
__global__ __launch_bounds__(256) void tcastW(
    const float* __restrict__ Wq, const float* __restrict__ Wk,
    const float* __restrict__ Wv,
    u16* __restrict__ WqT, u16* __restrict__ WkT, u16* __restrict__ WvT)
{
    __shared__ float t[64][68];
    const int sel = blockIdx.z >> 4, hz = blockIdx.z & 15;
    const float* in = (sel == 0) ? Wq : (sel == 1) ? Wk : Wv;
    u16* out = (sel == 0) ? WqT : (sel == 1) ? WkT : WvT;
    const long mb = (long)hz * 65536;
    const int r0 = blockIdx.x * 64;
    const int tid = threadIdx.x;
    const int rr = tid >> 4, c4 = (tid & 15) * 4;

    #pragma unroll
    for (int p = 0; p < 4; ++p) {
        float4 v = *(const float4*)(in + mb + (long)(r0 + p * 16 + rr) * 64 + c4);
        *(float4*)&t[p * 16 + rr][c4] = v;
    }
    __syncthreads();
    #pragma unroll
    for (int p = 0; p < 4; ++p) {
        const int oc = p * 16 + rr;          // output row (col of W, 0..63)
        const int r4 = (tid & 15) * 4;
        ushort4 o;
        o.x = f2b(t[r4 + 0][oc]); o.y = f2b(t[r4 + 1][oc]);
        o.z = f2b(t[r4 + 2][oc]); o.w = f2b(t[r4 + 3][oc]);
        *(ushort4*)(out + mb + (long)oc * 1024 + r0 + r4) = o;
    }
}

// ---------------------------------------------------------------------------
// Wo transpose-cast: fp32 [1024][1024] -> bf16 [1024][1024]^T. grid (16,16).
// ---------------------------------------------------------------------------
__global__ __launch_bounds__(256) void tcastWo(
    const float* __restrict__ in, u16* __restrict__ out)
{
    __shared__ float t[64][68];
    const int r0 = blockIdx.x * 64, c0 = blockIdx.y * 64;
    const int tid = threadIdx.x;
    const int rr = tid >> 4, c4 = (tid & 15) * 4;

    #pragma unroll
    for (int p = 0; p < 4; ++p) {
        float4 v = *(const float4*)(in + (long)(r0 + p * 16 + rr) * 1024 + c0 + c4);
        *(float4*)&t[p * 16 + rr][c4] = v;
    }
    __syncthreads();
    #pragma unroll
    for (int p = 0; p < 4; ++p) {
        const int oc = p * 16 + rr;
        const int r4 = (tid & 15) * 4;
        ushort4 o;
        o.x = f2b(t[r4 + 0][oc]); o.y = f2b(t[r4 + 1][oc]);
        o.z = f2b(t[r4 + 2][oc]); o.w = f2b(t[r4 + 3][oc]);
        *(ushort4*)(out + (long)(c0 + oc) * 1024 + r0 + r4) = o;
    }
}

// ---------------------------------------------------------------------------
// GEMM body macro pieces shared by proj3 / gemm_out.
// 128x128 tile, 4 waves 2x2, XOR-swizzled LDS (chunk stored at chunk^(row&7)).
// ---------------------------------------------------------------------------
#define GEMM_CORE(A_, BT_)                                                     \
    __shared__ u16 As[128 * 64];                                               \
    __shared__ u16 Bs[128 * 64];                                               \
    const int tid = threadIdx.x, lane = tid & 63, w = tid >> 6;                \
    const int m0 = blockIdx.y * 128, n0 = blockIdx.x * 128;                    \
    const int wm = (w >> 1) * 64, wn = (w & 1) * 64;                           \
    const int fr = lane & 15, quad = lane >> 4;                                \
    f32x4 acc[4][4];                                                           \
    const f32x4 zero = {0.f, 0.f, 0.f, 0.f};                                   \
    _Pragma("unroll")                                                          \
    for (int mi = 0; mi < 4; ++mi)                                             \
        _Pragma("unroll")                                                      \
        for (int ni = 0; ni < 4; ++ni) acc[mi][ni] = zero;                     \
    const int srow = lane >> 3;                                                \
    const int schk = (lane & 7) ^ (srow & 7);   /* swizzled source chunk */    \
    const long ga = (long)(m0 + srow) * 1024 + schk * 8;                       \
    const long gb = (long)(n0 + srow) * 1024 + schk * 8;                       \
    const int f7 = fr & 7;                                                     \
    for (int k0 = 0; k0 < 1024; k0 += 64) {                                    \
        __syncthreads();                                                       \
        _Pragma("unroll")                                                      \
        for (int i2 = 0; i2 < 4; ++i2) {                                       \
            const int i = w * 4 + i2;                                          \
            glds16(A_ + ga + (long)i * 8 * 1024 + k0, &As[i * 512]);           \
            glds16(BT_ + gb + (long)i * 8 * 1024 + k0, &Bs[i * 512]);          \
        }                                                                      \
        __syncthreads();                                                       \
        _Pragma("unroll")                                                      \
        for (int kc = 0; kc < 2; ++kc) {                                       \
            const int pos = ((kc * 4 + quad) ^ f7) * 8;                        \
            bf16x8 af[4], bfr[4];                                              \
            _Pragma("unroll")                                                  \
            for (int mi = 0; mi < 4; ++mi)                                     \
                af[mi] = *(const bf16x8*)&As[(wm + mi * 16 + fr) * 64 + pos];  \
            _Pragma("unroll")                                                  \
            for (int ni = 0; ni < 4; ++ni)                                     \
                bfr[ni] = *(const bf16x8*)&Bs[(wn + ni * 16 + fr) * 64 + pos]; \
            _Pragma("unroll")                                                  \
            for (int mi = 0; mi < 4; ++mi)                                     \
                _Pragma("unroll")                                              \
                for (int ni = 0; ni < 4; ++ni)                                 \
                    acc[mi][ni] = __builtin_amdgcn_mfma_f32_16x16x32_bf16(     \
                        af[mi], bfr[ni], acc[mi][ni], 0, 0, 0);                \
        }                                                                      \
    }

// Projections (z: 0=Q, 1=K, 2=V). OUT: z<2 -> [bh][s][64]; z==2 -> [bh][64][s]
__global__ __launch_bounds__(256) void proj3(
    const u16* __restrict__ Qb, const u16* __restrict__ Kb,
    const u16* __restrict__ Vb,
    const u16* __restrict__ WqT, const u16* __restrict__ WkT,
    const u16* __restrict__ WvT,
    const float* __restrict__ bq, const float* __restrict__ bk,
    const float* __restrict__ bv,
    u16* __restrict__ QWb, u16* __restrict__ KWb, u16* __restrict__ VWb)
{
    const int z = blockIdx.z;
    const u16* A  = (z == 0) ? Qb : (z == 1) ? Kb : Vb;
    const u16* BT = (z == 0) ? WqT : (z == 1) ? WkT : WvT;
    const float* bias = (z == 0) ? bq : (z == 1) ? bk : bv;
    u16* Cu = (z == 0) ? QWb : (z == 1) ? KWb : VWb;

    GEMM_CORE(A, BT)

    #pragma unroll
    for (int mi = 0; mi < 4; ++mi) {
        #pragma unroll
        for (int ni = 0; ni < 4; ++ni) {
            #pragma unroll
            for (int r = 0; r < 4; ++r) {
                const int m = m0 + wm + mi * 16 + quad * 4 + r;
                const int c = n0 + wn + ni * 16 + fr;
                const float v = acc[mi][ni][r] + bias[c];
                const int b = m >> 11, s = m & 2047, h = c >> 6, k = c & 63;
                if (z != 2)
                    Cu[((long)(b * 16 + h) * 2048 + s) * 64 + k] = f2b(v);
                else
                    Cu[((long)(b * 16 + h) * 64 + k) * 2048 + s] = f2b(v);
            }
        }
    }
}

// Output projection: fp32 out = ctx(bf16) @ WoT^T + bo
__global__ __launch_bounds__(256) void gemm_out(
    const u16* __restrict__ A, const u16* __restrict__ BT,
    const float* __restrict__ bias, float* __restrict__ Cf)
{
    GEMM_CORE(A, BT)

    #pragma unroll
    for (int mi = 0; mi < 4; ++mi) {
        #pragma unroll
        for (int ni = 0; ni < 4; ++ni) {
            #pragma unroll
            for (int r = 0; r < 4; ++r) {
                const int m = m0 + wm + mi * 16 + quad * 4 + r;
                const int c = n0 + wn + ni * 16 + fr;
                Cf[(long)m * 1024 + c] = acc[mi][ni][r] + bias[c];
            }
        }
    }
}

// ---------------------------------------------------------------------------
// MFMA flash attention v3. QW/KW: [bh][2048][64]; VW: [bh][64][2048] (bf16).
//   Block = 4 waves, 64 q rows (16 per wave). t-tiles of 64, double-buffered
//   kt/vt staging (STAGE(t+1) issued before computing tile t; the end-of-loop
//   __syncthreads provides vmcnt(0)+barrier).
//   Swapped QK^T: mfma(K,Q) -> lane holds S[t=sub*16+quad*4+r][q=fr], so the
//   4 reg values are t-consecutive -> cvt_pk_bf16 + one ds_write_b64 per sub
//   (was 16 scalar b16 stores + 64 VALU f2b ops per 16 P-values).
//   Non-centered softmax: p = exp(s); l accumulated via MFMA with ones-B.
//   attn = softmax/64/2 -> ctx scaled by 1/(l*128). XOR-swizzled kt/vt.
// ---------------------------------------------------------------------------
__global__ __launch_bounds__(256) void attn_mfma(
    const u16* __restrict__ QW, const u16* __restrict__ KW,
    const u16* __restrict__ VW, u16* __restrict__ ctxb)
{
    __shared__ u16 kt[2][64 * 64];   // [buf][t][k] swizzled, 16 KB
    __shared__ u16 vt[2][64 * 64];   // [buf][d][t] swizzled, 16 KB
    __shared__ u16 ps[4][16 * 72];   // per-wave P [q][t], stride 72, 9 KB

    const int tid = threadIdx.x, lane = tid & 63, w = tid >> 6;
    const int bh = blockIdx.y, b = bh >> 4, h = bh & 15;
    const int q0 = blockIdx.x * 64;
    const int fr = lane & 15, quad = lane >> 4;
    const int f7 = fr & 7;

    // Q fragments (B-operand of swapped QK^T): rows q = fr, k = quad*8+j
    const u16* qp = QW + ((long)bh * 2048 + q0 + w * 16 + fr) * 64;
    const bf16x8 aQ0 = *(const bf16x8*)(qp + quad * 8);
    const bf16x8 aQ1 = *(const bf16x8*)(qp + 32 + quad * 8);

    const f32x4 zero = {0.f, 0.f, 0.f, 0.f};
    f32x4 acc[4], lac = zero;
    #pragma unroll
    for (int d = 0; d < 4; ++d) acc[d] = zero;
    bf16x8 bones;
    #pragma unroll
    for (int j = 0; j < 8; ++j) bones[j] = (short)0x3F80;  // bf16 1.0

    const int srow = lane >> 3;
    const int schk = (lane & 7) ^ (srow & 7);   // swizzled source chunk
    const long kgb = (long)bh * (2048 * 64);
    const long vgb = (long)bh * (64 * 2048);

#define ATTN_STAGE(p_, t_)                                                    \
    _Pragma("unroll")                                                         \
    for (int i2 = 0; i2 < 2; ++i2) {                                          \
        const int i = w * 2 + i2;                                             \
        glds16(KW + kgb + (long)((t_) + i * 8 + srow) * 64 + schk * 8,        \
               &kt[p_][i * 512]);                                             \
        glds16(VW + vgb + (long)(i * 8 + srow) * 2048 + (t_) + schk * 8,      \
               &vt[p_][i * 512]);                                             \
    }

    ATTN_STAGE(0, 0)
    __syncthreads();                 // drains vmcnt(0) before s_barrier

    const int pos0 = (quad ^ f7) * 8;      // swizzled chunk {quad}
    const int pos1 = pos0 ^ 32;            // swizzled chunk {quad+4}
    u16* pw = ps[w];

    for (int t0 = 0; t0 < 2048; t0 += 64) {
        const int p = (t0 >> 6) & 1;
        if (t0 + 64 < 2048) { ATTN_STAGE(p ^ 1, t0 + 64) }   // prefetch next

        const u16* ktp = kt[p];
        const u16* vtp = vt[p];

        // ---- swapped QK^T: D[t][q], lane(fr=q,quad) holds t=sub*16+quad*4+r
        f32x4 sc[4];
        __builtin_amdgcn_s_setprio(1);
        #pragma unroll
        for (int sub = 0; sub < 4; ++sub) {
            const int row = (sub * 16 + fr) * 64;
            bf16x8 k0 = *(const bf16x8*)&ktp[row + pos0];
            bf16x8 k1 = *(const bf16x8*)&ktp[row + pos1];
            f32x4 z = __builtin_amdgcn_mfma_f32_16x16x32_bf16(k0, aQ0, zero, 0, 0, 0);
            sc[sub]  = __builtin_amdgcn_mfma_f32_16x16x32_bf16(k1, aQ1, z, 0, 0, 0);
        }
        __builtin_amdgcn_s_setprio(0);

        // ---- exp + packed bf16 convert + vectorized P store (b64) ----
        #pragma unroll
        for (int sub = 0; sub < 4; ++sub) {
            float e0 = __expf(sc[sub][0]);
            float e1 = __expf(sc[sub][1]);
            float e2 = __expf(sc[sub][2]);
            float e3 = __expf(sc[sub][3]);
            u32 lo, hi;
            asm("v_cvt_pk_bf16_f32 %0, %1, %2" : "=v"(lo) : "v"(e0), "v"(e1));
            asm("v_cvt_pk_bf16_f32 %0, %1, %2" : "=v"(hi) : "v"(e2), "v"(e3));
            uint2 pk2; pk2.x = lo; pk2.y = hi;
            *(uint2*)&pw[fr * 72 + sub * 16 + quad * 4] = pk2;   // ds_write_b64
        }
        __asm__ volatile("s_waitcnt lgkmcnt(0)" ::: "memory");

        // ---- l (ones-MFMA) + PV ----
        const bf16x8 aP0 = *(const bf16x8*)&pw[fr * 72 + quad * 8];
        const bf16x8 aP1 = *(const bf16x8*)&pw[fr * 72 + 32 + quad * 8];
        __builtin_amdgcn_s_setprio(1);
        lac = __builtin_amdgcn_mfma_f32_16x16x32_bf16(aP0, bones, lac, 0, 0, 0);
        lac = __builtin_amdgcn_mfma_f32_16x16x32_bf16(aP1, bones, lac, 0, 0, 0);
        #pragma unroll
        for (int d = 0; d < 4; ++d) {
            const int row = (d * 16 + fr) * 64;
            bf16x8 v0 = *(const bf16x8*)&vtp[row + pos0];
            bf16x8 v1 = *(const bf16x8*)&vtp[row + pos1];
            acc[d] = __builtin_amdgcn_mfma_f32_16x16x32_bf16(aP0, v0, acc[d], 0, 0, 0);
            acc[d] = __builtin_amdgcn_mfma_f32_16x16x32_bf16(aP1, v1, acc[d], 0, 0, 0);
        }
        __builtin_amdgcn_s_setprio(0);
        __syncthreads();             // drains vmcnt (prefetch) + lgkm, barrier
    }

    // epilogue: ctx = acc/(l*128), row = q0 + w*16 + quad*4 + r
    #pragma unroll
    for (int r = 0; r < 4; ++r) {
        const float scl = 1.0f / (lac[r] * 128.0f);
        const long row = (long)b * 2048 + q0 + w * 16 + quad * 4 + r;
        #pragma unroll
        for (int d = 0; d < 4; ++d)
            ctxb[row * 1024 + h * 64 + d * 16 + fr] = f2b(acc[d][r] * scl);
    }
}

// ---------------------------------------------------------------------------
extern "C" void kernel_launch(void* const* d_in, const int* in_sizes, int n_in,
                              void* d_out, int out_size, void* d_ws, size_t ws_size,
                              hipStream_t stream) {
    (void)in_sizes; (void)n_in; (void)out_size; (void)ws_size;

    const float* Q  = (const float*)d_in[0];
    const float* K  = (const float*)d_in[1];
    const float* V  = (const float*)d_in[2];
    const float* Wq = (const float*)d_in[3];
    const float* bq = (const float*)d_in[4];
    const float* Wk = (const float*)d_in[5];
    const float* bk = (const float*)d_in[6];
    const float* Wv = (const float*)d_in[7];
    const float* bv = (const float*)d_in[8];
    const float* Wo = (const float*)d_in[9];
    const float* bo = (const float*)d_in[10];
    float* out = (float*)d_out;

    u16* ws  = (u16*)d_ws;                // 64 MB total
    u16* Qb  = ws;                        // 4096x1024
    u16* Kb  = Qb  + 4194304;
    u16* Vb  = Kb  + 4194304;
    u16* WqT = Vb  + 4194304;             // [16][64][1024]
    u16* WkT = WqT + 1048576;
    u16* WvT = WkT + 1048576;
    u16* WoT = WvT + 1048576;             // [1024][1024]
    u16* QWb = WoT + 1048576;             // [32][2048][64]
    u16* KWb = QWb + 4194304;             // [32][2048][64]
    u16* VWb = KWb + 4194304;             // [32][64][2048]
    u16* ctx = VWb + 4194304;             // [4096][1024]

    cast3<<<dim3(1024, 1, 3), 256, 0, stream>>>(Q, K, V, Qb, Kb, Vb);
    tcastW<<<dim3(16, 1, 48), 256, 0, stream>>>(Wq, Wk, Wv, WqT, WkT, WvT);
    tcastWo<<<dim3(16, 16), 256, 0, stream>>>(Wo, WoT);

    proj3<<<dim3(8, 32, 3), 256, 0, stream>>>(Qb, Kb, Vb, WqT, WkT, WvT,
                                              bq, bk, bv, QWb, KWb, VWb);

    attn_mfma<<<dim3(32, 32), 256, 0, stream>>>(QWb, KWb, VWb, ctx);

    gemm_out<<<dim3(8, 32), 256, 0, stream>>>(ctx, WoT, bo, out);
}

// Round 2
// 250.152 us; speedup vs baseline: 1.1068x; 1.1068x over previous
//
#include <hip/hip_runtime.h>

typedef unsigned short u16;
typedef unsigned int u32;
typedef __attribute__((ext_vector_type(8))) short bf16x8;
typedef __attribute__((ext_vector_type(4))) float f32x4;

__device__ __forceinline__ u16 f2b(float f) {
    union { float f; u32 u; } v; v.f = f;
    return (u16)((v.u + 0x7FFF + ((v.u >> 16) & 1)) >> 16);  // RNE
}

__device__ __forceinline__ void glds16(const u16* g, u16* l) {
    __builtin_amdgcn_global_load_lds(
        (const __attribute__((address_space(1))) void*)g,
        (__attribute__((address_space(3))) void*)l, 16, 0, 0);
}

// ---------------------------------------------------------------------------
// fp32 -> bf16 flat casts for Q, K, V (grid.z selects input). n4 = 1048576.
// ---------------------------------------------------------------------------
__global__ __launch_bounds__(256) void cast3(
    const float* __restrict__ Q, const float* __restrict__ K,
    const float* __restrict__ V,
    u16* __restrict__ Qb, u16* __restrict__ Kb, u16* __restrict__ Vb)
{
    const float* in = (blockIdx.z == 0) ? Q : (blockIdx.z == 1) ? K : V;
    u16* out = (blockIdx.z == 0) ? Qb : (blockIdx.z == 1) ? Kb : Vb;
    const int n4 = 1048576;
    const int stride = gridDim.x * 256;
    for (int i = blockIdx.x * 256 + threadIdx.x; i < n4; i += stride) {
        float4 v = ((const float4*)in)[i];
        ushort4 o;
        o.x = f2b(v.x); o.y = f2b(v.y); o.z = f2b(v.z); o.w = f2b(v.w);
        ((ushort4*)out)[i] = o;
    }
}

// ---------------------------------------------------------------------------
// Per-head weight transpose-cast: fp32 [16][1024][64] -> bf16 [16][64][1024].
// grid (16, 1, 48): z>>4 selects Wq/Wk/Wv, z&15 = head.
// ---------------------------------------------------------------------------
__global__ __launch_bounds__(256) void tcastW(
    const float* __restrict__ Wq, const float* __restrict__ Wk,
    const float* __restrict__ Wv,
    u16* __restrict__ WqT, u16* __restrict__ WkT, u16* __restrict__ WvT)
{
    __shared__ float t[64][68];
    const int sel = blockIdx.z >> 4, hz = blockIdx.z & 15;
    const float* in = (sel == 0) ? Wq : (sel == 1) ? Wk : Wv;
    u16* out = (sel == 0) ? WqT : (sel == 1) ? WkT : WvT;
    const long mb = (long)hz * 65536;
    const int r0 = blockIdx.x * 64;
    const int tid = threadIdx.x;
    const int rr = tid >> 4, c4 = (tid & 15) * 4;

    #pragma unroll
    for (int p = 0; p < 4; ++p) {
        float4 v = *(const float4*)(in + mb + (long)(r0 + p * 16 + rr) * 64 + c4);
        *(float4*)&t[p * 16 + rr][c4] = v;
    }
    __syncthreads();
    #pragma unroll
    for (int p = 0; p < 4; ++p) {
        const int oc = p * 16 + rr;          // output row (col of W, 0..63)
        const int r4 = (tid & 15) * 4;
        ushort4 o;
        o.x = f2b(t[r4 + 0][oc]); o.y = f2b(t[r4 + 1][oc]);
        o.z = f2b(t[r4 + 2][oc]); o.w = f2b(t[r4 + 3][oc]);
        *(ushort4*)(out + mb + (long)oc * 1024 + r0 + r4) = o;
    }
}

// ---------------------------------------------------------------------------
// Wo transpose-cast: fp32 [1024][1024] -> bf16 [1024][1024]^T. grid (16,16).
// ---------------------------------------------------------------------------
__global__ __launch_bounds__(256) void tcastWo(
    const float* __restrict__ in, u16* __restrict__ out)
{
    __shared__ float t[64][68];
    const int r0 = blockIdx.x * 64, c0 = blockIdx.y * 64;
    const int tid = threadIdx.x;
    const int rr = tid >> 4, c4 = (tid & 15) * 4;

    #pragma unroll
    for (int p = 0; p < 4; ++p) {
        float4 v = *(const float4*)(in + (long)(r0 + p * 16 + rr) * 1024 + c0 + c4);
        *(float4*)&t[p * 16 + rr][c4] = v;
    }
    __syncthreads();
    #pragma unroll
    for (int p = 0; p < 4; ++p) {
        const int oc = p * 16 + rr;
        const int r4 = (tid & 15) * 4;
        ushort4 o;
        o.x = f2b(t[r4 + 0][oc]); o.y = f2b(t[r4 + 1][oc]);
        o.z = f2b(t[r4 + 2][oc]); o.w = f2b(t[r4 + 3][oc]);
        *(ushort4*)(out + (long)(c0 + oc) * 1024 + r0 + r4) = o;
    }
}

// ---------------------------------------------------------------------------
// GEMM body macro pieces shared by proj3 / gemm_out.
// 128x128 tile, 4 waves 2x2, XOR-swizzled LDS (chunk stored at chunk^(row&7)).
// ---------------------------------------------------------------------------
#define GEMM_CORE(A_, BT_)                                                     \
    __shared__ u16 As[128 * 64];                                               \
    __shared__ u16 Bs[128 * 64];                                               \
    const int tid = threadIdx.x, lane = tid & 63, w = tid >> 6;                \
    const int m0 = blockIdx.y * 128, n0 = blockIdx.x * 128;                    \
    const int wm = (w >> 1) * 64, wn = (w & 1) * 64;                           \
    const int fr = lane & 15, quad = lane >> 4;                                \
    f32x4 acc[4][4];                                                           \
    const f32x4 zero = {0.f, 0.f, 0.f, 0.f};                                   \
    _Pragma("unroll")                                                          \
    for (int mi = 0; mi < 4; ++mi)                                             \
        _Pragma("unroll")                                                      \
        for (int ni = 0; ni < 4; ++ni) acc[mi][ni] = zero;                     \
    const int srow = lane >> 3;                                                \
    const int schk = (lane & 7) ^ (srow & 7);   /* swizzled source chunk */    \
    const long ga = (long)(m0 + srow) * 1024 + schk * 8;                       \
    const long gb = (long)(n0 + srow) * 1024 + schk * 8;                       \
    const int f7 = fr & 7;                                                     \
    for (int k0 = 0; k0 < 1024; k0 += 64) {                                    \
        __syncthreads();                                                       \
        _Pragma("unroll")                                                      \
        for (int i2 = 0; i2 < 4; ++i2) {                                       \
            const int i = w * 4 + i2;                                          \
            glds16(A_ + ga + (long)i * 8 * 1024 + k0, &As[i * 512]);           \
            glds16(BT_ + gb + (long)i * 8 * 1024 + k0, &Bs[i * 512]);          \
        }                                                                      \
        __syncthreads();                                                       \
        _Pragma("unroll")                                                      \
        for (int kc = 0; kc < 2; ++kc) {                                       \
            const int pos = ((kc * 4 + quad) ^ f7) * 8;                        \
            bf16x8 af[4], bfr[4];                                              \
            _Pragma("unroll")                                                  \
            for (int mi = 0; mi < 4; ++mi)                                     \
                af[mi] = *(const bf16x8*)&As[(wm + mi * 16 + fr) * 64 + pos];  \
            _Pragma("unroll")                                                  \
            for (int ni = 0; ni < 4; ++ni)                                     \
                bfr[ni] = *(const bf16x8*)&Bs[(wn + ni * 16 + fr) * 64 + pos]; \
            _Pragma("unroll")                                                  \
            for (int mi = 0; mi < 4; ++mi)                                     \
                _Pragma("unroll")                                              \
                for (int ni = 0; ni < 4; ++ni)                                 \
                    acc[mi][ni] = __builtin_amdgcn_mfma_f32_16x16x32_bf16(     \
                        af[mi], bfr[ni], acc[mi][ni], 0, 0, 0);                \
        }                                                                      \
    }

// Projections (z: 0=Q, 1=K, 2=V). OUT: z<2 -> [bh][s][64]; z==2 -> [bh][64][s]
__global__ __launch_bounds__(256) void proj3(
    const u16* __restrict__ Qb, const u16* __restrict__ Kb,
    const u16* __restrict__ Vb,
    const u16* __restrict__ WqT, const u16* __restrict__ WkT,
    const u16* __restrict__ WvT,
    const float* __restrict__ bq, const float* __restrict__ bk,
    const float* __restrict__ bv,
    u16* __restrict__ QWb, u16* __restrict__ KWb, u16* __restrict__ VWb)
{
    const int z = blockIdx.z;
    const u16* A  = (z == 0) ? Qb : (z == 1) ? Kb : Vb;
    const u16* BT = (z == 0) ? WqT : (z == 1) ? WkT : WvT;
    const float* bias = (z == 0) ? bq : (z == 1) ? bk : bv;
    u16* Cu = (z == 0) ? QWb : (z == 1) ? KWb : VWb;

    GEMM_CORE(A, BT)

    #pragma unroll
    for (int mi = 0; mi < 4; ++mi) {
        #pragma unroll
        for (int ni = 0; ni < 4; ++ni) {
            #pragma unroll
            for (int r = 0; r < 4; ++r) {
                const int m = m0 + wm + mi * 16 + quad * 4 + r;
                const int c = n0 + wn + ni * 16 + fr;
                const float v = acc[mi][ni][r] + bias[c];
                const int b = m >> 11, s = m & 2047, h = c >> 6, k = c & 63;
                if (z != 2)
                    Cu[((long)(b * 16 + h) * 2048 + s) * 64 + k] = f2b(v);
                else
                    Cu[((long)(b * 16 + h) * 64 + k) * 2048 + s] = f2b(v);
            }
        }
    }
}

// Output projection: fp32 out = ctx(bf16) @ WoT^T + bo
__global__ __launch_bounds__(256) void gemm_out(
    const u16* __restrict__ A, const u16* __restrict__ BT,
    const float* __restrict__ bias, float* __restrict__ Cf)
{
    GEMM_CORE(A, BT)

    #pragma unroll
    for (int mi = 0; mi < 4; ++mi) {
        #pragma unroll
        for (int ni = 0; ni < 4; ++ni) {
            #pragma unroll
            for (int r = 0; r < 4; ++r) {
                const int m = m0 + wm + mi * 16 + quad * 4 + r;
                const int c = n0 + wn + ni * 16 + fr;
                Cf[(long)m * 1024 + c] = acc[mi][ni][r] + bias[c];
            }
        }
    }
}

// ---------------------------------------------------------------------------
// MFMA flash attention v4. QW/KW: [bh][2048][64]; VW: [bh][64][2048] (bf16).
//   Block = 4 waves, 128 q rows (32 per wave as 2 sets of 16) -- round-0
//   structure restored for staging amortization (36 MFMA per wave-tile).
//   Kept from v3: double-buffered kt/vt prefetch, swapped QK^T (mfma(K,Q)
//   puts S[t][q] with t-consecutive regs -> cvt_pk_bf16 + ds_write_b64 P
//   stores), s_setprio around MFMA clusters.
//   Non-centered softmax: p = exp(s); l accumulated via MFMA with ones-B.
//   attn = softmax/64/2 -> ctx scaled by 1/(l*128). XOR-swizzled kt/vt.
// ---------------------------------------------------------------------------
__global__ __launch_bounds__(256) void attn_mfma(
    const u16* __restrict__ QW, const u16* __restrict__ KW,
    const u16* __restrict__ VW, u16* __restrict__ ctxb)
{
    __shared__ u16 kt[2][64 * 64];   // [buf][t][k] swizzled, 16 KB
    __shared__ u16 vt[2][64 * 64];   // [buf][d][t] swizzled, 16 KB
    __shared__ u16 ps[4][32 * 72];   // per-wave P [q][t], stride 72, 18 KB

    const int tid = threadIdx.x, lane = tid & 63, w = tid >> 6;
    const int bh = blockIdx.y, b = bh >> 4, h = bh & 15;
    const int q0 = blockIdx.x * 128;
    const int fr = lane & 15, quad = lane >> 4;
    const int f7 = fr & 7;

    // Q fragments (B-operand of swapped QK^T): 2 q-sets of 16 rows, q = fr
    bf16x8 aQ[2][2];
    #pragma unroll
    for (int s = 0; s < 2; ++s) {
        const u16* qp = QW + ((long)bh * 2048 + q0 + w * 32 + s * 16 + fr) * 64;
        aQ[s][0] = *(const bf16x8*)(qp + quad * 8);
        aQ[s][1] = *(const bf16x8*)(qp + 32 + quad * 8);
    }

    const f32x4 zero = {0.f, 0.f, 0.f, 0.f};
    f32x4 acc[2][4], lac[2];
    #pragma unroll
    for (int s = 0; s < 2; ++s) {
        lac[s] = zero;
        #pragma unroll
        for (int d = 0; d < 4; ++d) acc[s][d] = zero;
    }
    bf16x8 bones;
    #pragma unroll
    for (int j = 0; j < 8; ++j) bones[j] = (short)0x3F80;  // bf16 1.0

    const int srow = lane >> 3;
    const int schk = (lane & 7) ^ (srow & 7);   // swizzled source chunk
    const long kgb = (long)bh * (2048 * 64);
    const long vgb = (long)bh * (64 * 2048);

#define ATTN_STAGE(p_, t_)                                                    \
    _Pragma("unroll")                                                         \
    for (int i2 = 0; i2 < 2; ++i2) {                                          \
        const int i = w * 2 + i2;                                             \
        glds16(KW + kgb + (long)((t_) + i * 8 + srow) * 64 + schk * 8,        \
               &kt[p_][i * 512]);                                             \
        glds16(VW + vgb + (long)(i * 8 + srow) * 2048 + (t_) + schk * 8,      \
               &vt[p_][i * 512]);                                             \
    }

    ATTN_STAGE(0, 0)
    __syncthreads();                 // drains vmcnt(0) before s_barrier

    const int pos0 = (quad ^ f7) * 8;      // swizzled chunk {quad}
    const int pos1 = pos0 ^ 32;            // swizzled chunk {quad+4}
    u16* pw = ps[w];

    for (int t0 = 0; t0 < 2048; t0 += 64) {
        const int p = (t0 >> 6) & 1;
        if (t0 + 64 < 2048) { ATTN_STAGE(p ^ 1, t0 + 64) }   // prefetch next

        const u16* ktp = kt[p];
        const u16* vtp = vt[p];

        // ---- swapped QK^T: D[t][q]; lane(fr=q,quad): t = sub*16+quad*4+r
        f32x4 sc[2][4];
        __builtin_amdgcn_s_setprio(1);
        #pragma unroll
        for (int s = 0; s < 2; ++s) {
            #pragma unroll
            for (int sub = 0; sub < 4; ++sub) {
                const int row = (sub * 16 + fr) * 64;
                bf16x8 k0 = *(const bf16x8*)&ktp[row + pos0];
                bf16x8 k1 = *(const bf16x8*)&ktp[row + pos1];
                f32x4 z = __builtin_amdgcn_mfma_f32_16x16x32_bf16(k0, aQ[s][0], zero, 0, 0, 0);
                sc[s][sub] = __builtin_amdgcn_mfma_f32_16x16x32_bf16(k1, aQ[s][1], z, 0, 0, 0);
            }
        }
        __builtin_amdgcn_s_setprio(0);

        // ---- exp + packed bf16 convert + vectorized P store (b64) ----
        // q-row = s*16+fr, t = sub*16 + quad*4 + {0..3}
        #pragma unroll
        for (int s = 0; s < 2; ++s) {
            #pragma unroll
            for (int sub = 0; sub < 4; ++sub) {
                float e0 = __expf(sc[s][sub][0]);
                float e1 = __expf(sc[s][sub][1]);
                float e2 = __expf(sc[s][sub][2]);
                float e3 = __expf(sc[s][sub][3]);
                u32 lo, hi;
                asm("v_cvt_pk_bf16_f32 %0, %1, %2" : "=v"(lo) : "v"(e0), "v"(e1));
                asm("v_cvt_pk_bf16_f32 %0, %1, %2" : "=v"(hi) : "v"(e2), "v"(e3));
                uint2 pk2; pk2.x = lo; pk2.y = hi;
                *(uint2*)&pw[(s * 16 + fr) * 72 + sub * 16 + quad * 4] = pk2;
            }
        }
        __asm__ volatile("s_waitcnt lgkmcnt(0)" ::: "memory");

        // ---- l (ones-MFMA) + PV for both q-sets ----
        __builtin_amdgcn_s_setprio(1);
        #pragma unroll
        for (int s = 0; s < 2; ++s) {
            const bf16x8 aP0 = *(const bf16x8*)&pw[(s * 16 + fr) * 72 + quad * 8];
            const bf16x8 aP1 = *(const bf16x8*)&pw[(s * 16 + fr) * 72 + 32 + quad * 8];
            lac[s] = __builtin_amdgcn_mfma_f32_16x16x32_bf16(aP0, bones, lac[s], 0, 0, 0);
            lac[s] = __builtin_amdgcn_mfma_f32_16x16x32_bf16(aP1, bones, lac[s], 0, 0, 0);
            #pragma unroll
            for (int d = 0; d < 4; ++d) {
                const int row = (d * 16 + fr) * 64;
                bf16x8 v0 = *(const bf16x8*)&vtp[row + pos0];
                bf16x8 v1 = *(const bf16x8*)&vtp[row + pos1];
                acc[s][d] = __builtin_amdgcn_mfma_f32_16x16x32_bf16(aP0, v0, acc[s][d], 0, 0, 0);
                acc[s][d] = __builtin_amdgcn_mfma_f32_16x16x32_bf16(aP1, v1, acc[s][d], 0, 0, 0);
            }
        }
        __builtin_amdgcn_s_setprio(0);
        __syncthreads();             // drains vmcnt (prefetch) + lgkm, barrier
    }

    // epilogue: ctx = acc/(l*128), row = q0 + w*32 + s*16 + quad*4 + r
    #pragma unroll
    for (int s = 0; s < 2; ++s) {
        #pragma unroll
        for (int r = 0; r < 4; ++r) {
            const float scl = 1.0f / (lac[s][r] * 128.0f);
            const long row = (long)b * 2048 + q0 + w * 32 + s * 16 + quad * 4 + r;
            #pragma unroll
            for (int d = 0; d < 4; ++d)
                ctxb[row * 1024 + h * 64 + d * 16 + fr] = f2b(acc[s][d][r] * scl);
        }
    }
}

// ---------------------------------------------------------------------------
extern "C" void kernel_launch(void* const* d_in, const int* in_sizes, int n_in,
                              void* d_out, int out_size, void* d_ws, size_t ws_size,
                              hipStream_t stream) {
    (void)in_sizes; (void)n_in; (void)out_size; (void)ws_size;

    const float* Q  = (const float*)d_in[0];
    const float* K  = (const float*)d_in[1];
    const float* V  = (const float*)d_in[2];
    const float* Wq = (const float*)d_in[3];
    const float* bq = (const float*)d_in[4];
    const float* Wk = (const float*)d_in[5];
    const float* bk = (const float*)d_in[6];
    const float* Wv = (const float*)d_in[7];
    const float* bv = (const float*)d_in[8];
    const float* Wo = (const float*)d_in[9];
    const float* bo = (const float*)d_in[10];
    float* out = (float*)d_out;

    u16* ws  = (u16*)d_ws;                // 64 MB total
    u16* Qb  = ws;                        // 4096x1024
    u16* Kb  = Qb  + 4194304;
    u16* Vb  = Kb  + 4194304;
    u16* WqT = Vb  + 4194304;             // [16][64][1024]
    u16* WkT = WqT + 1048576;
    u16* WvT = WkT + 1048576;
    u16* WoT = WvT + 1048576;             // [1024][1024]
    u16* QWb = WoT + 1048576;             // [32][2048][64]
    u16* KWb = QWb + 4194304;             // [32][2048][64]
    u16* VWb = KWb + 4194304;             // [32][64][2048]
    u16* ctx = VWb + 4194304;             // [4096][1024]

    cast3<<<dim3(1024, 1, 3), 256, 0, stream>>>(Q, K, V, Qb, Kb, Vb);
    tcastW<<<dim3(16, 1, 48), 256, 0, stream>>>(Wq, Wk, Wv, WqT, WkT, WvT);
    tcastWo<<<dim3(16, 16), 256, 0, stream>>>(Wo, WoT);

    proj3<<<dim3(8, 32, 3), 256, 0, stream>>>(Qb, Kb, Vb, WqT, WkT, WvT,
                                              bq, bk, bv, QWb, KWb, VWb);

    attn_mfma<<<dim3(16, 32), 256, 0, stream>>>(QWb, KWb, VWb, ctx);

    gemm_out<<<dim3(8, 32), 256, 0, stream>>>(ctx, WoT, bo, out);
}

// Round 3
// 229.956 us; speedup vs baseline: 1.2040x; 1.0878x over previous
//
#include <hip/hip_runtime.h>

typedef unsigned short u16;
typedef unsigned int u32;
typedef __attribute__((ext_vector_type(8))) short bf16x8;
typedef __attribute__((ext_vector_type(4))) float f32x4;

__device__ __forceinline__ u16 f2b(float f) {
    union { float f; u32 u; } v; v.f = f;
    return (u16)((v.u + 0x7FFF + ((v.u >> 16) & 1)) >> 16);  // RNE
}

__device__ __forceinline__ void glds16(const u16* g, u16* l) {
    __builtin_amdgcn_global_load_lds(
        (const __attribute__((address_space(1))) void*)g,
        (__attribute__((address_space(3))) void*)l, 16, 0, 0);
}

// ---------------------------------------------------------------------------
// fp32 -> bf16 flat casts for Q, K, V (grid.z selects input). n4 = 1048576.
// ---------------------------------------------------------------------------
__global__ __launch_bounds__(256) void cast3(
    const float* __restrict__ Q, const float* __restrict__ K,
    const float* __restrict__ V,
    u16* __restrict__ Qb, u16* __restrict__ Kb, u16* __restrict__ Vb)
{
    const float* in = (blockIdx.z == 0) ? Q : (blockIdx.z == 1) ? K : V;
    u16* out = (blockIdx.z == 0) ? Qb : (blockIdx.z == 1) ? Kb : Vb;
    const int n4 = 1048576;
    const int stride = gridDim.x * 256;
    for (int i = blockIdx.x * 256 + threadIdx.x; i < n4; i += stride) {
        float4 v = ((const float4*)in)[i];
        ushort4 o;
        o.x = f2b(v.x); o.y = f2b(v.y); o.z = f2b(v.z); o.w = f2b(v.w);
        ((ushort4*)out)[i] = o;
    }
}

// ---------------------------------------------------------------------------
// Per-head weight transpose-cast: fp32 [16][1024][64] -> bf16 [16][64][1024].
// grid (16, 1, 48): z>>4 selects Wq/Wk/Wv, z&15 = head.
// ---------------------------------------------------------------------------
__global__ __launch_bounds__(256) void tcastW(
    const float* __restrict__ Wq, const float* __restrict__ Wk,
    const float* __restrict__ Wv,
    u16* __restrict__ WqT, u16* __restrict__ WkT, u16* __restrict__ WvT)
{
    __shared__ float t[64][68];
    const int sel = blockIdx.z >> 4, hz = blockIdx.z & 15;
    const float* in = (sel == 0) ? Wq : (sel == 1) ? Wk : Wv;
    u16* out = (sel == 0) ? WqT : (sel == 1) ? WkT : WvT;
    const long mb = (long)hz * 65536;
    const int r0 = blockIdx.x * 64;
    const int tid = threadIdx.x;
    const int rr = tid >> 4, c4 = (tid & 15) * 4;

    #pragma unroll
    for (int p = 0; p < 4; ++p) {
        float4 v = *(const float4*)(in + mb + (long)(r0 + p * 16 + rr) * 64 + c4);
        *(float4*)&t[p * 16 + rr][c4] = v;
    }
    __syncthreads();
    #pragma unroll
    for (int p = 0; p < 4; ++p) {
        const int oc = p * 16 + rr;          // output row (col of W, 0..63)
        const int r4 = (tid & 15) * 4;
        ushort4 o;
        o.x = f2b(t[r4 + 0][oc]); o.y = f2b(t[r4 + 1][oc]);
        o.z = f2b(t[r4 + 2][oc]); o.w = f2b(t[r4 + 3][oc]);
        *(ushort4*)(out + mb + (long)oc * 1024 + r0 + r4) = o;
    }
}

// ---------------------------------------------------------------------------
// Wo transpose-cast: fp32 [1024][1024] -> bf16 [1024][1024]^T. grid (16,16).
// ---------------------------------------------------------------------------
__global__ __launch_bounds__(256) void tcastWo(
    const float* __restrict__ in, u16* __restrict__ out)
{
    __shared__ float t[64][68];
    const int r0 = blockIdx.x * 64, c0 = blockIdx.y * 64;
    const int tid = threadIdx.x;
    const int rr = tid >> 4, c4 = (tid & 15) * 4;

    #pragma unroll
    for (int p = 0; p < 4; ++p) {
        float4 v = *(const float4*)(in + (long)(r0 + p * 16 + rr) * 1024 + c0 + c4);
        *(float4*)&t[p * 16 + rr][c4] = v;
    }
    __syncthreads();
    #pragma unroll
    for (int p = 0; p < 4; ++p) {
        const int oc = p * 16 + rr;
        const int r4 = (tid & 15) * 4;
        ushort4 o;
        o.x = f2b(t[r4 + 0][oc]); o.y = f2b(t[r4 + 1][oc]);
        o.z = f2b(t[r4 + 2][oc]); o.w = f2b(t[r4 + 3][oc]);
        *(ushort4*)(out + (long)(c0 + oc) * 1024 + r0 + r4) = o;
    }
}

// ---------------------------------------------------------------------------
// GEMM body shared by proj3 / gemm_out.
// 128x128 tile, 4 waves 2x2, XOR-swizzled LDS (chunk stored at chunk^(row&7)).
// v2: double-buffered prefetch (STAGE(k+1) issued before computing tile k,
// single barrier per K-step drains vmcnt+lgkm), s_setprio around MFMA cluster.
// Grid mapping: x = m-tile (32), y = n-tile (8) so that linear-id%8 XCD
// round-robin keeps each XCD's working set (4 A-panels + whole B) in its L2.
// ---------------------------------------------------------------------------
#define GEMM_STAGE(A_, BT_, p_, k_)                                            \
    _Pragma("unroll")                                                          \
    for (int i2 = 0; i2 < 4; ++i2) {                                           \
        const int i = w * 4 + i2;                                              \
        glds16(A_ + ga + (long)i * 8 * 1024 + (k_), &As[p_][i * 512]);         \
        glds16(BT_ + gb + (long)i * 8 * 1024 + (k_), &Bs[p_][i * 512]);        \
    }

#define GEMM_CORE(A_, BT_)                                                     \
    __shared__ u16 As[2][128 * 64];                                            \
    __shared__ u16 Bs[2][128 * 64];                                            \
    const int tid = threadIdx.x, lane = tid & 63, w = tid >> 6;                \
    const int m0 = blockIdx.x * 128, n0 = blockIdx.y * 128;                    \
    const int wm = (w >> 1) * 64, wn = (w & 1) * 64;                           \
    const int fr = lane & 15, quad = lane >> 4;                                \
    f32x4 acc[4][4];                                                           \
    const f32x4 zero = {0.f, 0.f, 0.f, 0.f};                                   \
    _Pragma("unroll")                                                          \
    for (int mi = 0; mi < 4; ++mi)                                             \
        _Pragma("unroll")                                                      \
        for (int ni = 0; ni < 4; ++ni) acc[mi][ni] = zero;                     \
    const int srow = lane >> 3;                                                \
    const int schk = (lane & 7) ^ (srow & 7);   /* swizzled source chunk */    \
    const long ga = (long)(m0 + srow) * 1024 + schk * 8;                       \
    const long gb = (long)(n0 + srow) * 1024 + schk * 8;                       \
    const int f7 = fr & 7;                                                     \
    GEMM_STAGE(A_, BT_, 0, 0)                                                  \
    __syncthreads();                                                           \
    for (int k0 = 0; k0 < 1024; k0 += 64) {                                    \
        const int p = (k0 >> 6) & 1;                                           \
        if (k0 + 64 < 1024) { GEMM_STAGE(A_, BT_, p ^ 1, k0 + 64) }            \
        __builtin_amdgcn_s_setprio(1);                                         \
        _Pragma("unroll")                                                      \
        for (int kc = 0; kc < 2; ++kc) {                                       \
            const int pos = ((kc * 4 + quad) ^ f7) * 8;                        \
            bf16x8 af[4], bfr[4];                                              \
            _Pragma("unroll")                                                  \
            for (int mi = 0; mi < 4; ++mi)                                     \
                af[mi] = *(const bf16x8*)&As[p][(wm + mi * 16 + fr) * 64 + pos]; \
            _Pragma("unroll")                                                  \
            for (int ni = 0; ni < 4; ++ni)                                     \
                bfr[ni] = *(const bf16x8*)&Bs[p][(wn + ni * 16 + fr) * 64 + pos]; \
            _Pragma("unroll")                                                  \
            for (int mi = 0; mi < 4; ++mi)                                     \
                _Pragma("unroll")                                              \
                for (int ni = 0; ni < 4; ++ni)                                 \
                    acc[mi][ni] = __builtin_amdgcn_mfma_f32_16x16x32_bf16(     \
                        af[mi], bfr[ni], acc[mi][ni], 0, 0, 0);                \
        }                                                                      \
        __builtin_amdgcn_s_setprio(0);                                         \
        __syncthreads();                                                       \
    }

// Projections (z: 0=Q, 1=K, 2=V). OUT: z<2 -> [bh][s][64]; z==2 -> [bh][64][s]
__global__ __launch_bounds__(256) void proj3(
    const u16* __restrict__ Qb, const u16* __restrict__ Kb,
    const u16* __restrict__ Vb,
    const u16* __restrict__ WqT, const u16* __restrict__ WkT,
    const u16* __restrict__ WvT,
    const float* __restrict__ bq, const float* __restrict__ bk,
    const float* __restrict__ bv,
    u16* __restrict__ QWb, u16* __restrict__ KWb, u16* __restrict__ VWb)
{
    const int z = blockIdx.z;
    const u16* A  = (z == 0) ? Qb : (z == 1) ? Kb : Vb;
    const u16* BT = (z == 0) ? WqT : (z == 1) ? WkT : WvT;
    const float* bias = (z == 0) ? bq : (z == 1) ? bk : bv;
    u16* Cu = (z == 0) ? QWb : (z == 1) ? KWb : VWb;

    GEMM_CORE(A, BT)

    #pragma unroll
    for (int mi = 0; mi < 4; ++mi) {
        #pragma unroll
        for (int ni = 0; ni < 4; ++ni) {
            const int mB = m0 + wm + mi * 16 + quad * 4;   // r = 0 row
            const int c  = n0 + wn + ni * 16 + fr;
            const int b = mB >> 11, s = mB & 2047, h = c >> 6, k = c & 63;
            const float bi = bias[c];
            if (z != 2) {
                #pragma unroll
                for (int r = 0; r < 4; ++r)
                    Cu[((long)(b * 16 + h) * 2048 + s + r) * 64 + k] =
                        f2b(acc[mi][ni][r] + bi);
            } else {
                ushort4 o;
                o.x = f2b(acc[mi][ni][0] + bi);
                o.y = f2b(acc[mi][ni][1] + bi);
                o.z = f2b(acc[mi][ni][2] + bi);
                o.w = f2b(acc[mi][ni][3] + bi);
                *(ushort4*)&Cu[((long)(b * 16 + h) * 64 + k) * 2048 + s] = o;
            }
        }
    }
}

// Output projection: fp32 out = ctx(bf16) @ WoT^T + bo
__global__ __launch_bounds__(256) void gemm_out(
    const u16* __restrict__ A, const u16* __restrict__ BT,
    const float* __restrict__ bias, float* __restrict__ Cf)
{
    GEMM_CORE(A, BT)

    #pragma unroll
    for (int mi = 0; mi < 4; ++mi) {
        #pragma unroll
        for (int ni = 0; ni < 4; ++ni) {
            #pragma unroll
            for (int r = 0; r < 4; ++r) {
                const int m = m0 + wm + mi * 16 + quad * 4 + r;
                const int c = n0 + wn + ni * 16 + fr;
                Cf[(long)m * 1024 + c] = acc[mi][ni][r] + bias[c];
            }
        }
    }
}

// ---------------------------------------------------------------------------
// MFMA flash attention v4. QW/KW: [bh][2048][64]; VW: [bh][64][2048] (bf16).
//   Block = 4 waves, 128 q rows (32 per wave as 2 sets of 16).
//   Double-buffered kt/vt prefetch, swapped QK^T (mfma(K,Q) puts S[t][q] with
//   t-consecutive regs -> cvt_pk_bf16 + ds_write_b64 P stores), s_setprio.
//   Non-centered softmax: p = exp(s); l accumulated via MFMA with ones-B.
//   attn = softmax/64/2 -> ctx scaled by 1/(l*128). XOR-swizzled kt/vt.
// ---------------------------------------------------------------------------
__global__ __launch_bounds__(256) void attn_mfma(
    const u16* __restrict__ QW, const u16* __restrict__ KW,
    const u16* __restrict__ VW, u16* __restrict__ ctxb)
{
    __shared__ u16 kt[2][64 * 64];   // [buf][t][k] swizzled, 16 KB
    __shared__ u16 vt[2][64 * 64];   // [buf][d][t] swizzled, 16 KB
    __shared__ u16 ps[4][32 * 72];   // per-wave P [q][t], stride 72, 18 KB

    const int tid = threadIdx.x, lane = tid & 63, w = tid >> 6;
    const int bh = blockIdx.y, b = bh >> 4, h = bh & 15;
    const int q0 = blockIdx.x * 128;
    const int fr = lane & 15, quad = lane >> 4;
    const int f7 = fr & 7;

    // Q fragments (B-operand of swapped QK^T): 2 q-sets of 16 rows, q = fr
    bf16x8 aQ[2][2];
    #pragma unroll
    for (int s = 0; s < 2; ++s) {
        const u16* qp = QW + ((long)bh * 2048 + q0 + w * 32 + s * 16 + fr) * 64;
        aQ[s][0] = *(const bf16x8*)(qp + quad * 8);
        aQ[s][1] = *(const bf16x8*)(qp + 32 + quad * 8);
    }

    const f32x4 zero = {0.f, 0.f, 0.f, 0.f};
    f32x4 acc[2][4], lac[2];
    #pragma unroll
    for (int s = 0; s < 2; ++s) {
        lac[s] = zero;
        #pragma unroll
        for (int d = 0; d < 4; ++d) acc[s][d] = zero;
    }
    bf16x8 bones;
    #pragma unroll
    for (int j = 0; j < 8; ++j) bones[j] = (short)0x3F80;  // bf16 1.0

    const int srow = lane >> 3;
    const int schk = (lane & 7) ^ (srow & 7);   // swizzled source chunk
    const long kgb = (long)bh * (2048 * 64);
    const long vgb = (long)bh * (64 * 2048);

#define ATTN_STAGE(p_, t_)                                                    \
    _Pragma("unroll")                                                         \
    for (int i2 = 0; i2 < 2; ++i2) {                                          \
        const int i = w * 2 + i2;                                             \
        glds16(KW + kgb + (long)((t_) + i * 8 + srow) * 64 + schk * 8,        \
               &kt[p_][i * 512]);                                             \
        glds16(VW + vgb + (long)(i * 8 + srow) * 2048 + (t_) + schk * 8,      \
               &vt[p_][i * 512]);                                             \
    }

    ATTN_STAGE(0, 0)
    __syncthreads();                 // drains vmcnt(0) before s_barrier

    const int pos0 = (quad ^ f7) * 8;      // swizzled chunk {quad}
    const int pos1 = pos0 ^ 32;            // swizzled chunk {quad+4}
    u16* pw = ps[w];

    for (int t0 = 0; t0 < 2048; t0 += 64) {
        const int p = (t0 >> 6) & 1;
        if (t0 + 64 < 2048) { ATTN_STAGE(p ^ 1, t0 + 64) }   // prefetch next

        const u16* ktp = kt[p];
        const u16* vtp = vt[p];

        // ---- swapped QK^T: D[t][q]; lane(fr=q,quad): t = sub*16+quad*4+r
        f32x4 sc[2][4];
        __builtin_amdgcn_s_setprio(1);
        #pragma unroll
        for (int s = 0; s < 2; ++s) {
            #pragma unroll
            for (int sub = 0; sub < 4; ++sub) {
                const int row = (sub * 16 + fr) * 64;
                bf16x8 k0 = *(const bf16x8*)&ktp[row + pos0];
                bf16x8 k1 = *(const bf16x8*)&ktp[row + pos1];
                f32x4 z = __builtin_amdgcn_mfma_f32_16x16x32_bf16(k0, aQ[s][0], zero, 0, 0, 0);
                sc[s][sub] = __builtin_amdgcn_mfma_f32_16x16x32_bf16(k1, aQ[s][1], z, 0, 0, 0);
            }
        }
        __builtin_amdgcn_s_setprio(0);

        // ---- exp + packed bf16 convert + vectorized P store (b64) ----
        // q-row = s*16+fr, t = sub*16 + quad*4 + {0..3}
        #pragma unroll
        for (int s = 0; s < 2; ++s) {
            #pragma unroll
            for (int sub = 0; sub < 4; ++sub) {
                float e0 = __expf(sc[s][sub][0]);
                float e1 = __expf(sc[s][sub][1]);
                float e2 = __expf(sc[s][sub][2]);
                float e3 = __expf(sc[s][sub][3]);
                u32 lo, hi;
                asm("v_cvt_pk_bf16_f32 %0, %1, %2" : "=v"(lo) : "v"(e0), "v"(e1));
                asm("v_cvt_pk_bf16_f32 %0, %1, %2" : "=v"(hi) : "v"(e2), "v"(e3));
                uint2 pk2; pk2.x = lo; pk2.y = hi;
                *(uint2*)&pw[(s * 16 + fr) * 72 + sub * 16 + quad * 4] = pk2;
            }
        }
        __asm__ volatile("s_waitcnt lgkmcnt(0)" ::: "memory");

        // ---- l (ones-MFMA) + PV for both q-sets ----
        __builtin_amdgcn_s_setprio(1);
        #pragma unroll
        for (int s = 0; s < 2; ++s) {
            const bf16x8 aP0 = *(const bf16x8*)&pw[(s * 16 + fr) * 72 + quad * 8];
            const bf16x8 aP1 = *(const bf16x8*)&pw[(s * 16 + fr) * 72 + 32 + quad * 8];
            lac[s] = __builtin_amdgcn_mfma_f32_16x16x32_bf16(aP0, bones, lac[s], 0, 0, 0);
            lac[s] = __builtin_amdgcn_mfma_f32_16x16x32_bf16(aP1, bones, lac[s], 0, 0, 0);
            #pragma unroll
            for (int d = 0; d < 4; ++d) {
                const int row = (d * 16 + fr) * 64;
                bf16x8 v0 = *(const bf16x8*)&vtp[row + pos0];
                bf16x8 v1 = *(const bf16x8*)&vtp[row + pos1];
                acc[s][d] = __builtin_amdgcn_mfma_f32_16x16x32_bf16(aP0, v0, acc[s][d], 0, 0, 0);
                acc[s][d] = __builtin_amdgcn_mfma_f32_16x16x32_bf16(aP1, v1, acc[s][d], 0, 0, 0);
            }
        }
        __builtin_amdgcn_s_setprio(0);
        __syncthreads();             // drains vmcnt (prefetch) + lgkm, barrier
    }

    // epilogue: ctx = acc/(l*128), row = q0 + w*32 + s*16 + quad*4 + r
    #pragma unroll
    for (int s = 0; s < 2; ++s) {
        #pragma unroll
        for (int r = 0; r < 4; ++r) {
            const float scl = 1.0f / (lac[s][r] * 128.0f);
            const long row = (long)b * 2048 + q0 + w * 32 + s * 16 + quad * 4 + r;
            #pragma unroll
            for (int d = 0; d < 4; ++d)
                ctxb[row * 1024 + h * 64 + d * 16 + fr] = f2b(acc[s][d][r] * scl);
        }
    }
}

// ---------------------------------------------------------------------------
extern "C" void kernel_launch(void* const* d_in, const int* in_sizes, int n_in,
                              void* d_out, int out_size, void* d_ws, size_t ws_size,
                              hipStream_t stream) {
    (void)in_sizes; (void)n_in; (void)out_size; (void)ws_size;

    const float* Q  = (const float*)d_in[0];
    const float* K  = (const float*)d_in[1];
    const float* V  = (const float*)d_in[2];
    const float* Wq = (const float*)d_in[3];
    const float* bq = (const float*)d_in[4];
    const float* Wk = (const float*)d_in[5];
    const float* bk = (const float*)d_in[6];
    const float* Wv = (const float*)d_in[7];
    const float* bv = (const float*)d_in[8];
    const float* Wo = (const float*)d_in[9];
    const float* bo = (const float*)d_in[10];
    float* out = (float*)d_out;

    u16* ws  = (u16*)d_ws;                // 64 MB total
    u16* Qb  = ws;                        // 4096x1024
    u16* Kb  = Qb  + 4194304;
    u16* Vb  = Kb  + 4194304;
    u16* WqT = Vb  + 4194304;             // [16][64][1024]
    u16* WkT = WqT + 1048576;
    u16* WvT = WkT + 1048576;
    u16* WoT = WvT + 1048576;             // [1024][1024]
    u16* QWb = WoT + 1048576;             // [32][2048][64]
    u16* KWb = QWb + 4194304;             // [32][2048][64]
    u16* VWb = KWb + 4194304;             // [32][64][2048]
    u16* ctx = VWb + 4194304;             // [4096][1024]

    cast3<<<dim3(1024, 1, 3), 256, 0, stream>>>(Q, K, V, Qb, Kb, Vb);
    tcastW<<<dim3(16, 1, 48), 256, 0, stream>>>(Wq, Wk, Wv, WqT, WkT, WvT);
    tcastWo<<<dim3(16, 16), 256, 0, stream>>>(Wo, WoT);

    // grid: x = m-tile (32), y = n-tile (8) for XCD L2 locality
    proj3<<<dim3(32, 8, 3), 256, 0, stream>>>(Qb, Kb, Vb, WqT, WkT, WvT,
                                              bq, bk, bv, QWb, KWb, VWb);

    attn_mfma<<<dim3(16, 32), 256, 0, stream>>>(QWb, KWb, VWb, ctx);

    gemm_out<<<dim3(32, 8), 256, 0, stream>>>(ctx, WoT, bo, out);
}

// Round 4
// 225.144 us; speedup vs baseline: 1.2297x; 1.0214x over previous
//
#include <hip/hip_runtime.h>

typedef unsigned short u16;
typedef unsigned int u32;
typedef __attribute__((ext_vector_type(8))) short bf16x8;
typedef __attribute__((ext_vector_type(4))) float f32x4;

__device__ __forceinline__ u16 f2b(float f) {
    union { float f; u32 u; } v; v.f = f;
    return (u16)((v.u + 0x7FFF + ((v.u >> 16) & 1)) >> 16);  // RNE
}

__device__ __forceinline__ void glds16(const u16* g, u16* l) {
    __builtin_amdgcn_global_load_lds(
        (const __attribute__((address_space(1))) void*)g,
        (__attribute__((address_space(3))) void*)l, 16, 0, 0);
}

// ---------------------------------------------------------------------------
// fp32 -> bf16 flat casts for Q, K, V (grid.z selects input). n4 = 1048576.
// ---------------------------------------------------------------------------
__global__ __launch_bounds__(256) void cast3(
    const float* __restrict__ Q, const float* __restrict__ K,
    const float* __restrict__ V,
    u16* __restrict__ Qb, u16* __restrict__ Kb, u16* __restrict__ Vb)
{
    const float* in = (blockIdx.z == 0) ? Q : (blockIdx.z == 1) ? K : V;
    u16* out = (blockIdx.z == 0) ? Qb : (blockIdx.z == 1) ? Kb : Vb;
    const int n4 = 1048576;
    const int stride = gridDim.x * 256;
    for (int i = blockIdx.x * 256 + threadIdx.x; i < n4; i += stride) {
        float4 v = ((const float4*)in)[i];
        ushort4 o;
        o.x = f2b(v.x); o.y = f2b(v.y); o.z = f2b(v.z); o.w = f2b(v.w);
        ((ushort4*)out)[i] = o;
    }
}

// ---------------------------------------------------------------------------
// Per-head weight transpose-cast: fp32 [16][1024][64] -> bf16 [16][64][1024].
// grid (16, 1, 48): z>>4 selects Wq/Wk/Wv, z&15 = head.
// ---------------------------------------------------------------------------
__global__ __launch_bounds__(256) void tcastW(
    const float* __restrict__ Wq, const float* __restrict__ Wk,
    const float* __restrict__ Wv,
    u16* __restrict__ WqT, u16* __restrict__ WkT, u16* __restrict__ WvT)
{
    __shared__ float t[64][68];
    const int sel = blockIdx.z >> 4, hz = blockIdx.z & 15;
    const float* in = (sel == 0) ? Wq : (sel == 1) ? Wk : Wv;
    u16* out = (sel == 0) ? WqT : (sel == 1) ? WkT : WvT;
    const long mb = (long)hz * 65536;
    const int r0 = blockIdx.x * 64;
    const int tid = threadIdx.x;
    const int rr = tid >> 4, c4 = (tid & 15) * 4;

    #pragma unroll
    for (int p = 0; p < 4; ++p) {
        float4 v = *(const float4*)(in + mb + (long)(r0 + p * 16 + rr) * 64 + c4);
        *(float4*)&t[p * 16 + rr][c4] = v;
    }
    __syncthreads();
    #pragma unroll
    for (int p = 0; p < 4; ++p) {
        const int oc = p * 16 + rr;          // output row (col of W, 0..63)
        const int r4 = (tid & 15) * 4;
        ushort4 o;
        o.x = f2b(t[r4 + 0][oc]); o.y = f2b(t[r4 + 1][oc]);
        o.z = f2b(t[r4 + 2][oc]); o.w = f2b(t[r4 + 3][oc]);
        *(ushort4*)(out + mb + (long)oc * 1024 + r0 + r4) = o;
    }
}

// ---------------------------------------------------------------------------
// Wo transpose-cast: fp32 [1024][1024] -> bf16 [1024][1024]^T. grid (16,16).
// ---------------------------------------------------------------------------
__global__ __launch_bounds__(256) void tcastWo(
    const float* __restrict__ in, u16* __restrict__ out)
{
    __shared__ float t[64][68];
    const int r0 = blockIdx.x * 64, c0 = blockIdx.y * 64;
    const int tid = threadIdx.x;
    const int rr = tid >> 4, c4 = (tid & 15) * 4;

    #pragma unroll
    for (int p = 0; p < 4; ++p) {
        float4 v = *(const float4*)(in + (long)(r0 + p * 16 + rr) * 1024 + c0 + c4);
        *(float4*)&t[p * 16 + rr][c4] = v;
    }
    __syncthreads();
    #pragma unroll
    for (int p = 0; p < 4; ++p) {
        const int oc = p * 16 + rr;
        const int r4 = (tid & 15) * 4;
        ushort4 o;
        o.x = f2b(t[r4 + 0][oc]); o.y = f2b(t[r4 + 1][oc]);
        o.z = f2b(t[r4 + 2][oc]); o.w = f2b(t[r4 + 3][oc]);
        *(ushort4*)(out + (long)(c0 + oc) * 1024 + r0 + r4) = o;
    }
}

// ---------------------------------------------------------------------------
// GEMM body shared by proj3 / gemm_out.
// 128x128 tile, 4 waves 2x2, XOR-swizzled LDS (chunk stored at chunk^(row&7)).
// Double-buffered prefetch (STAGE(k+1) issued before computing tile k,
// single barrier per K-step drains vmcnt+lgkm), s_setprio around MFMA cluster.
// Grid mapping: x = m-tile (32), y = n-tile (8) so that linear-id%8 XCD
// round-robin keeps each XCD's working set (4 A-panels + whole B) in its L2.
// ---------------------------------------------------------------------------
#define GEMM_STAGE(A_, BT_, p_, k_)                                            \
    _Pragma("unroll")                                                          \
    for (int i2 = 0; i2 < 4; ++i2) {                                           \
        const int i = w * 4 + i2;                                              \
        glds16(A_ + ga + (long)i * 8 * 1024 + (k_), &As[p_][i * 512]);         \
        glds16(BT_ + gb + (long)i * 8 * 1024 + (k_), &Bs[p_][i * 512]);        \
    }

#define GEMM_CORE(A_, BT_)                                                     \
    __shared__ u16 As[2][128 * 64];                                            \
    __shared__ u16 Bs[2][128 * 64];                                            \
    const int tid = threadIdx.x, lane = tid & 63, w = tid >> 6;                \
    const int m0 = blockIdx.x * 128, n0 = blockIdx.y * 128;                    \
    const int wm = (w >> 1) * 64, wn = (w & 1) * 64;                           \
    const int fr = lane & 15, quad = lane >> 4;                                \
    f32x4 acc[4][4];                                                           \
    const f32x4 zero = {0.f, 0.f, 0.f, 0.f};                                   \
    _Pragma("unroll")                                                          \
    for (int mi = 0; mi < 4; ++mi)                                             \
        _Pragma("unroll")                                                      \
        for (int ni = 0; ni < 4; ++ni) acc[mi][ni] = zero;                     \
    const int srow = lane >> 3;                                                \
    const int schk = (lane & 7) ^ (srow & 7);   /* swizzled source chunk */    \
    const long ga = (long)(m0 + srow) * 1024 + schk * 8;                       \
    const long gb = (long)(n0 + srow) * 1024 + schk * 8;                       \
    const int f7 = fr & 7;                                                     \
    GEMM_STAGE(A_, BT_, 0, 0)                                                  \
    __syncthreads();                                                           \
    for (int k0 = 0; k0 < 1024; k0 += 64) {                                    \
        const int p = (k0 >> 6) & 1;                                           \
        if (k0 + 64 < 1024) { GEMM_STAGE(A_, BT_, p ^ 1, k0 + 64) }            \
        __builtin_amdgcn_s_setprio(1);                                         \
        _Pragma("unroll")                                                      \
        for (int kc = 0; kc < 2; ++kc) {                                       \
            const int pos = ((kc * 4 + quad) ^ f7) * 8;                        \
            bf16x8 af[4], bfr[4];                                              \
            _Pragma("unroll")                                                  \
            for (int mi = 0; mi < 4; ++mi)                                     \
                af[mi] = *(const bf16x8*)&As[p][(wm + mi * 16 + fr) * 64 + pos]; \
            _Pragma("unroll")                                                  \
            for (int ni = 0; ni < 4; ++ni)                                     \
                bfr[ni] = *(const bf16x8*)&Bs[p][(wn + ni * 16 + fr) * 64 + pos]; \
            _Pragma("unroll")                                                  \
            for (int mi = 0; mi < 4; ++mi)                                     \
                _Pragma("unroll")                                              \
                for (int ni = 0; ni < 4; ++ni)                                 \
                    acc[mi][ni] = __builtin_amdgcn_mfma_f32_16x16x32_bf16(     \
                        af[mi], bfr[ni], acc[mi][ni], 0, 0, 0);                \
        }                                                                      \
        __builtin_amdgcn_s_setprio(0);                                         \
        __syncthreads();                                                       \
    }

// Projections (z: 0=Q, 1=K, 2=V). OUT: z<2 -> [bh][s][64]; z==2 -> [bh][64][s]
__global__ __launch_bounds__(256) void proj3(
    const u16* __restrict__ Qb, const u16* __restrict__ Kb,
    const u16* __restrict__ Vb,
    const u16* __restrict__ WqT, const u16* __restrict__ WkT,
    const u16* __restrict__ WvT,
    const float* __restrict__ bq, const float* __restrict__ bk,
    const float* __restrict__ bv,
    u16* __restrict__ QWb, u16* __restrict__ KWb, u16* __restrict__ VWb)
{
    const int z = blockIdx.z;
    const u16* A  = (z == 0) ? Qb : (z == 1) ? Kb : Vb;
    const u16* BT = (z == 0) ? WqT : (z == 1) ? WkT : WvT;
    const float* bias = (z == 0) ? bq : (z == 1) ? bk : bv;
    u16* Cu = (z == 0) ? QWb : (z == 1) ? KWb : VWb;

    GEMM_CORE(A, BT)

    #pragma unroll
    for (int mi = 0; mi < 4; ++mi) {
        #pragma unroll
        for (int ni = 0; ni < 4; ++ni) {
            const int mB = m0 + wm + mi * 16 + quad * 4;   // r = 0 row
            const int c  = n0 + wn + ni * 16 + fr;
            const int b = mB >> 11, s = mB & 2047, h = c >> 6, k = c & 63;
            const float bi = bias[c];
            if (z != 2) {
                #pragma unroll
                for (int r = 0; r < 4; ++r)
                    Cu[((long)(b * 16 + h) * 2048 + s + r) * 64 + k] =
                        f2b(acc[mi][ni][r] + bi);
            } else {
                ushort4 o;
                o.x = f2b(acc[mi][ni][0] + bi);
                o.y = f2b(acc[mi][ni][1] + bi);
                o.z = f2b(acc[mi][ni][2] + bi);
                o.w = f2b(acc[mi][ni][3] + bi);
                *(ushort4*)&Cu[((long)(b * 16 + h) * 64 + k) * 2048 + s] = o;
            }
        }
    }
}

// Output projection: fp32 out = ctx(bf16) @ WoT^T + bo
__global__ __launch_bounds__(256) void gemm_out(
    const u16* __restrict__ A, const u16* __restrict__ BT,
    const float* __restrict__ bias, float* __restrict__ Cf)
{
    GEMM_CORE(A, BT)

    #pragma unroll
    for (int mi = 0; mi < 4; ++mi) {
        #pragma unroll
        for (int ni = 0; ni < 4; ++ni) {
            #pragma unroll
            for (int r = 0; r < 4; ++r) {
                const int m = m0 + wm + mi * 16 + quad * 4 + r;
                const int c = n0 + wn + ni * 16 + fr;
                Cf[(long)m * 1024 + c] = acc[mi][ni][r] + bias[c];
            }
        }
    }
}

// ---------------------------------------------------------------------------
// MFMA flash attention v5. QW/KW: [bh][2048][64]; VW: [bh][64][2048] (bf16).
//   Block = 4 waves, 128 q rows (32 per wave as 2 sets of 16).
//   v5: distance-2 prefetch over 3 LDS buffers with COUNTED vmcnt(4) + raw
//   s_barrier (T3/T4): each wave issues exactly 4 glds per tile, so
//   vmcnt(4) retires precisely the current tile's loads while the next
//   tile's 4 stay in flight across the barrier. Single barrier per iter.
//   XCD colocate remap: linear-id%8 = XCD; give each XCD 4 heads x 16
//   q-tiles so K/V working set (2 MB) fits its 4 MB L2.
//   Swapped QK^T (mfma(K,Q) -> t-consecutive regs -> cvt_pk + b64 P store),
//   s_setprio around MFMA clusters. Non-centered softmax: p = exp(s),
//   l via ones-MFMA; ctx scaled by 1/(l*128). XOR-swizzled kt/vt.
// ---------------------------------------------------------------------------
__global__ __launch_bounds__(256) void attn_mfma(
    const u16* __restrict__ QW, const u16* __restrict__ KW,
    const u16* __restrict__ VW, u16* __restrict__ ctxb)
{
    __shared__ u16 kt[3][64 * 64];   // [buf][t][k] swizzled, 24 KB
    __shared__ u16 vt[3][64 * 64];   // [buf][d][t] swizzled, 24 KB
    __shared__ u16 ps[4][32 * 72];   // per-wave P [q][t], stride 72, 18 KB

    const int tid = threadIdx.x, lane = tid & 63, w = tid >> 6;
    // XCD colocate: id%8 is the XCD (round-robin dispatch). Bijection:
    // bh = (id&7)*4 + ((id>>3)&3), qt = id>>5  (512 blocks total).
    const int id = blockIdx.x + gridDim.x * blockIdx.y;
    const int bh = (id & 7) * 4 + ((id >> 3) & 3);
    const int q0 = (id >> 5) * 128;
    const int b = bh >> 4, h = bh & 15;
    const int fr = lane & 15, quad = lane >> 4;
    const int f7 = fr & 7;

    // Q fragments (B-operand of swapped QK^T): 2 q-sets of 16 rows, q = fr
    bf16x8 aQ[2][2];
    #pragma unroll
    for (int s = 0; s < 2; ++s) {
        const u16* qp = QW + ((long)bh * 2048 + q0 + w * 32 + s * 16 + fr) * 64;
        aQ[s][0] = *(const bf16x8*)(qp + quad * 8);
        aQ[s][1] = *(const bf16x8*)(qp + 32 + quad * 8);
    }

    const f32x4 zero = {0.f, 0.f, 0.f, 0.f};
    f32x4 acc[2][4], lac[2];
    #pragma unroll
    for (int s = 0; s < 2; ++s) {
        lac[s] = zero;
        #pragma unroll
        for (int d = 0; d < 4; ++d) acc[s][d] = zero;
    }
    bf16x8 bones;
    #pragma unroll
    for (int j = 0; j < 8; ++j) bones[j] = (short)0x3F80;  // bf16 1.0

    const int srow = lane >> 3;
    const int schk = (lane & 7) ^ (srow & 7);   // swizzled source chunk
    const long kgb = (long)bh * (2048 * 64);
    const long vgb = (long)bh * (64 * 2048);

#define ATTN_STAGE(p_, t_)                                                    \
    _Pragma("unroll")                                                         \
    for (int i2 = 0; i2 < 2; ++i2) {                                          \
        const int i = w * 2 + i2;                                             \
        glds16(KW + kgb + (long)((t_) + i * 8 + srow) * 64 + schk * 8,        \
               &kt[p_][i * 512]);                                             \
        glds16(VW + vgb + (long)(i * 8 + srow) * 2048 + (t_) + schk * 8,      \
               &vt[p_][i * 512]);                                             \
    }

    // Prologue: tiles 0 and 1 in flight (8 outstanding vm ops/wave).
    ATTN_STAGE(0, 0)
    ATTN_STAGE(1, 64)

    const int pos0 = (quad ^ f7) * 8;      // swizzled chunk {quad}
    const int pos1 = pos0 ^ 32;            // swizzled chunk {quad+4}
    u16* pw = ps[w];

    for (int t0 = 0; t0 < 2048; t0 += 64) {
        const int it = t0 >> 6;
        const int p = it % 3;

        // Counted wait: retire current tile's 4 loads; next tile's 4 stay
        // in flight across the barrier (T4). Last iter fully drains.
        if (t0 + 64 < 2048) {
            __asm__ volatile("s_waitcnt vmcnt(4)" ::: "memory");
        } else {
            __asm__ volatile("s_waitcnt vmcnt(0)" ::: "memory");
        }
        __builtin_amdgcn_s_barrier();
        __asm__ volatile("" ::: "memory");
        __builtin_amdgcn_sched_barrier(0);

        // Stage tile i+2 into the buffer last read at iter i-1 (safe: those
        // reads completed before this barrier).
        if (t0 + 128 < 2048) { ATTN_STAGE((it + 2) % 3, t0 + 128) }

        const u16* ktp = kt[p];
        const u16* vtp = vt[p];

        // ---- swapped QK^T: D[t][q]; lane(fr=q,quad): t = sub*16+quad*4+r
        f32x4 sc[2][4];
        __builtin_amdgcn_s_setprio(1);
        #pragma unroll
        for (int s = 0; s < 2; ++s) {
            #pragma unroll
            for (int sub = 0; sub < 4; ++sub) {
                const int row = (sub * 16 + fr) * 64;
                bf16x8 k0 = *(const bf16x8*)&ktp[row + pos0];
                bf16x8 k1 = *(const bf16x8*)&ktp[row + pos1];
                f32x4 z = __builtin_amdgcn_mfma_f32_16x16x32_bf16(k0, aQ[s][0], zero, 0, 0, 0);
                sc[s][sub] = __builtin_amdgcn_mfma_f32_16x16x32_bf16(k1, aQ[s][1], z, 0, 0, 0);
            }
        }
        __builtin_amdgcn_s_setprio(0);

        // ---- exp + packed bf16 convert + vectorized P store (b64) ----
        // q-row = s*16+fr, t = sub*16 + quad*4 + {0..3}
        #pragma unroll
        for (int s = 0; s < 2; ++s) {
            #pragma unroll
            for (int sub = 0; sub < 4; ++sub) {
                float e0 = __expf(sc[s][sub][0]);
                float e1 = __expf(sc[s][sub][1]);
                float e2 = __expf(sc[s][sub][2]);
                float e3 = __expf(sc[s][sub][3]);
                u32 lo, hi;
                asm("v_cvt_pk_bf16_f32 %0, %1, %2" : "=v"(lo) : "v"(e0), "v"(e1));
                asm("v_cvt_pk_bf16_f32 %0, %1, %2" : "=v"(hi) : "v"(e2), "v"(e3));
                uint2 pk2; pk2.x = lo; pk2.y = hi;
                *(uint2*)&pw[(s * 16 + fr) * 72 + sub * 16 + quad * 4] = pk2;
            }
        }
        __asm__ volatile("s_waitcnt lgkmcnt(0)" ::: "memory");
        __builtin_amdgcn_sched_barrier(0);

        // ---- l (ones-MFMA) + PV for both q-sets ----
        __builtin_amdgcn_s_setprio(1);
        #pragma unroll
        for (int s = 0; s < 2; ++s) {
            const bf16x8 aP0 = *(const bf16x8*)&pw[(s * 16 + fr) * 72 + quad * 8];
            const bf16x8 aP1 = *(const bf16x8*)&pw[(s * 16 + fr) * 72 + 32 + quad * 8];
            lac[s] = __builtin_amdgcn_mfma_f32_16x16x32_bf16(aP0, bones, lac[s], 0, 0, 0);
            lac[s] = __builtin_amdgcn_mfma_f32_16x16x32_bf16(aP1, bones, lac[s], 0, 0, 0);
            #pragma unroll
            for (int d = 0; d < 4; ++d) {
                const int row = (d * 16 + fr) * 64;
                bf16x8 v0 = *(const bf16x8*)&vtp[row + pos0];
                bf16x8 v1 = *(const bf16x8*)&vtp[row + pos1];
                acc[s][d] = __builtin_amdgcn_mfma_f32_16x16x32_bf16(aP0, v0, acc[s][d], 0, 0, 0);
                acc[s][d] = __builtin_amdgcn_mfma_f32_16x16x32_bf16(aP1, v1, acc[s][d], 0, 0, 0);
            }
        }
        __builtin_amdgcn_s_setprio(0);
        // no trailing barrier: next iter's counted-wait + barrier covers it
    }

    // epilogue: ctx = acc/(l*128), row = q0 + w*32 + s*16 + quad*4 + r
    #pragma unroll
    for (int s = 0; s < 2; ++s) {
        #pragma unroll
        for (int r = 0; r < 4; ++r) {
            const float scl = 1.0f / (lac[s][r] * 128.0f);
            const long row = (long)b * 2048 + q0 + w * 32 + s * 16 + quad * 4 + r;
            #pragma unroll
            for (int d = 0; d < 4; ++d)
                ctxb[row * 1024 + h * 64 + d * 16 + fr] = f2b(acc[s][d][r] * scl);
        }
    }
}

// ---------------------------------------------------------------------------
extern "C" void kernel_launch(void* const* d_in, const int* in_sizes, int n_in,
                              void* d_out, int out_size, void* d_ws, size_t ws_size,
                              hipStream_t stream) {
    (void)in_sizes; (void)n_in; (void)out_size; (void)ws_size;

    const float* Q  = (const float*)d_in[0];
    const float* K  = (const float*)d_in[1];
    const float* V  = (const float*)d_in[2];
    const float* Wq = (const float*)d_in[3];
    const float* bq = (const float*)d_in[4];
    const float* Wk = (const float*)d_in[5];
    const float* bk = (const float*)d_in[6];
    const float* Wv = (const float*)d_in[7];
    const float* bv = (const float*)d_in[8];
    const float* Wo = (const float*)d_in[9];
    const float* bo = (const float*)d_in[10];
    float* out = (float*)d_out;

    u16* ws  = (u16*)d_ws;                // 64 MB total
    u16* Qb  = ws;                        // 4096x1024
    u16* Kb  = Qb  + 4194304;
    u16* Vb  = Kb  + 4194304;
    u16* WqT = Vb  + 4194304;             // [16][64][1024]
    u16* WkT = WqT + 1048576;
    u16* WvT = WkT + 1048576;
    u16* WoT = WvT + 1048576;             // [1024][1024]
    u16* QWb = WoT + 1048576;             // [32][2048][64]
    u16* KWb = QWb + 4194304;             // [32][2048][64]
    u16* VWb = KWb + 4194304;             // [32][64][2048]
    u16* ctx = VWb + 4194304;             // [4096][1024]

    cast3<<<dim3(1024, 1, 3), 256, 0, stream>>>(Q, K, V, Qb, Kb, Vb);
    tcastW<<<dim3(16, 1, 48), 256, 0, stream>>>(Wq, Wk, Wv, WqT, WkT, WvT);
    tcastWo<<<dim3(16, 16), 256, 0, stream>>>(Wo, WoT);

    // grid: x = m-tile (32), y = n-tile (8) for XCD L2 locality
    proj3<<<dim3(32, 8, 3), 256, 0, stream>>>(Qb, Kb, Vb, WqT, WkT, WvT,
                                              bq, bk, bv, QWb, KWb, VWb);

    attn_mfma<<<dim3(16, 32), 256, 0, stream>>>(QWb, KWb, VWb, ctx);

    gemm_out<<<dim3(32, 8), 256, 0, stream>>>(ctx, WoT, bo, out);
}

// Round 8
// 221.119 us; speedup vs baseline: 1.2521x; 1.0182x over previous
//
#include <hip/hip_runtime.h>

typedef unsigned short u16;
typedef unsigned int u32;
typedef __attribute__((ext_vector_type(8))) short bf16x8;
typedef __attribute__((ext_vector_type(4))) float f32x4;

__device__ __forceinline__ u16 f2b(float f) {
    union { float f; u32 u; } v; v.f = f;
    return (u16)((v.u + 0x7FFF + ((v.u >> 16) & 1)) >> 16);  // RNE
}

__device__ __forceinline__ void glds16(const u16* g, u16* l) {
    __builtin_amdgcn_global_load_lds(
        (const __attribute__((address_space(1))) void*)g,
        (__attribute__((address_space(3))) void*)l, 16, 0, 0);
}

// ---------------------------------------------------------------------------
// Fused prep: grid (1024, 1, 5).
//   z<3 : fp32 -> bf16 flat cast of Q/K/V (n4 = 1048576 float4's each).
//   z==3: per-head weight transpose-cast fp32 [16][1024][64] -> [16][64][1024]
//         (x<768: r0i = x&15, sel = x>>8, hz = (x>>4)&15).
//   z==4: Wo transpose-cast fp32 [1024][1024] -> ^T (x<256).
// NOTE: inputs are cast to bf16 UNMODIFIED — no pre-scaling before the cast
// (round-5 lesson; under bisect suspicion together with the ps relayout).
// ---------------------------------------------------------------------------
__global__ __launch_bounds__(256) void prep(
    const float* __restrict__ Q, const float* __restrict__ K,
    const float* __restrict__ V,
    const float* __restrict__ Wq, const float* __restrict__ Wk,
    const float* __restrict__ Wv, const float* __restrict__ Wo,
    u16* __restrict__ Qb, u16* __restrict__ Kb, u16* __restrict__ Vb,
    u16* __restrict__ WqT, u16* __restrict__ WkT, u16* __restrict__ WvT,
    u16* __restrict__ WoT)
{
    __shared__ float t[64][68];
    const int z = blockIdx.z, x = blockIdx.x, tid = threadIdx.x;

    if (z < 3) {
        const float* in = (z == 0) ? Q : (z == 1) ? K : V;
        u16* out = (z == 0) ? Qb : (z == 1) ? Kb : Vb;
        const int n4 = 1048576;
        const int stride = 1024 * 256;
        for (int i = x * 256 + tid; i < n4; i += stride) {
            float4 v = ((const float4*)in)[i];
            ushort4 o;
            o.x = f2b(v.x); o.y = f2b(v.y); o.z = f2b(v.z); o.w = f2b(v.w);
            ((ushort4*)out)[i] = o;
        }
        return;
    }

    const int rr = tid >> 4, c4 = (tid & 15) * 4;

    if (z == 3) {
        if (x >= 768) return;
        const int sel = x >> 8, hz = (x >> 4) & 15;
        const float* in = (sel == 0) ? Wq : (sel == 1) ? Wk : Wv;
        u16* out = (sel == 0) ? WqT : (sel == 1) ? WkT : WvT;
        const long mb = (long)hz * 65536;
        const int r0 = (x & 15) * 64;

        #pragma unroll
        for (int p = 0; p < 4; ++p) {
            float4 v = *(const float4*)(in + mb + (long)(r0 + p * 16 + rr) * 64 + c4);
            *(float4*)&t[p * 16 + rr][c4] = v;
        }
        __syncthreads();
        #pragma unroll
        for (int p = 0; p < 4; ++p) {
            const int oc = p * 16 + rr;
            const int r4 = (tid & 15) * 4;
            ushort4 o;
            o.x = f2b(t[r4 + 0][oc]); o.y = f2b(t[r4 + 1][oc]);
            o.z = f2b(t[r4 + 2][oc]); o.w = f2b(t[r4 + 3][oc]);
            *(ushort4*)(out + mb + (long)oc * 1024 + r0 + r4) = o;
        }
        return;
    }

    // z == 4: Wo
    if (x >= 256) return;
    const int r0 = (x & 15) * 64, c0 = (x >> 4) * 64;
    #pragma unroll
    for (int p = 0; p < 4; ++p) {
        float4 v = *(const float4*)(Wo + (long)(r0 + p * 16 + rr) * 1024 + c0 + c4);
        *(float4*)&t[p * 16 + rr][c4] = v;
    }
    __syncthreads();
    #pragma unroll
    for (int p = 0; p < 4; ++p) {
        const int oc = p * 16 + rr;
        const int r4 = (tid & 15) * 4;
        ushort4 o;
        o.x = f2b(t[r4 + 0][oc]); o.y = f2b(t[r4 + 1][oc]);
        o.z = f2b(t[r4 + 2][oc]); o.w = f2b(t[r4 + 3][oc]);
        *(ushort4*)(WoT + (long)(c0 + oc) * 1024 + r0 + r4) = o;
    }
}

// ---------------------------------------------------------------------------
// GEMM body shared by proj3 / gemm_out.
// 128x128 tile, 4 waves 2x2, XOR-swizzled LDS (chunk stored at chunk^(row&7)).
// Double-buffered prefetch, single barrier per K-step, s_setprio around MFMA.
// Grid mapping: x = m-tile (32), y = n-tile (8) for XCD L2 locality.
// ---------------------------------------------------------------------------
#define GEMM_STAGE(A_, BT_, p_, k_)                                            \
    _Pragma("unroll")                                                          \
    for (int i2 = 0; i2 < 4; ++i2) {                                           \
        const int i = w * 4 + i2;                                              \
        glds16(A_ + ga + (long)i * 8 * 1024 + (k_), &As[p_][i * 512]);         \
        glds16(BT_ + gb + (long)i * 8 * 1024 + (k_), &Bs[p_][i * 512]);        \
    }

#define GEMM_CORE(A_, BT_)                                                     \
    __shared__ u16 As[2][128 * 64];                                            \
    __shared__ u16 Bs[2][128 * 64];                                            \
    const int tid = threadIdx.x, lane = tid & 63, w = tid >> 6;                \
    const int m0 = blockIdx.x * 128, n0 = blockIdx.y * 128;                    \
    const int wm = (w >> 1) * 64, wn = (w & 1) * 64;                           \
    const int fr = lane & 15, quad = lane >> 4;                                \
    f32x4 acc[4][4];                                                           \
    const f32x4 zero = {0.f, 0.f, 0.f, 0.f};                                   \
    _Pragma("unroll")                                                          \
    for (int mi = 0; mi < 4; ++mi)                                             \
        _Pragma("unroll")                                                      \
        for (int ni = 0; ni < 4; ++ni) acc[mi][ni] = zero;                     \
    const int srow = lane >> 3;                                                \
    const int schk = (lane & 7) ^ (srow & 7);   /* swizzled source chunk */    \
    const long ga = (long)(m0 + srow) * 1024 + schk * 8;                       \
    const long gb = (long)(n0 + srow) * 1024 + schk * 8;                       \
    const int f7 = fr & 7;                                                     \
    GEMM_STAGE(A_, BT_, 0, 0)                                                  \
    __syncthreads();                                                           \
    for (int k0 = 0; k0 < 1024; k0 += 64) {                                    \
        const int p = (k0 >> 6) & 1;                                           \
        if (k0 + 64 < 1024) { GEMM_STAGE(A_, BT_, p ^ 1, k0 + 64) }            \
        __builtin_amdgcn_s_setprio(1);                                         \
        _Pragma("unroll")                                                      \
        for (int kc = 0; kc < 2; ++kc) {                                       \
            const int pos = ((kc * 4 + quad) ^ f7) * 8;                        \
            bf16x8 af[4], bfr[4];                                              \
            _Pragma("unroll")                                                  \
            for (int mi = 0; mi < 4; ++mi)                                     \
                af[mi] = *(const bf16x8*)&As[p][(wm + mi * 16 + fr) * 64 + pos]; \
            _Pragma("unroll")                                                  \
            for (int ni = 0; ni < 4; ++ni)                                     \
                bfr[ni] = *(const bf16x8*)&Bs[p][(wn + ni * 16 + fr) * 64 + pos]; \
            _Pragma("unroll")                                                  \
            for (int mi = 0; mi < 4; ++mi)                                     \
                _Pragma("unroll")                                              \
                for (int ni = 0; ni < 4; ++ni)                                 \
                    acc[mi][ni] = __builtin_amdgcn_mfma_f32_16x16x32_bf16(     \
                        af[mi], bfr[ni], acc[mi][ni], 0, 0, 0);                \
        }                                                                      \
        __builtin_amdgcn_s_setprio(0);                                         \
        __syncthreads();                                                       \
    }

// Projections (z: 0=Q, 1=K, 2=V). OUT: z<2 -> [bh][s][64]; z==2 -> [bh][64][s]
__global__ __launch_bounds__(256) void proj3(
    const u16* __restrict__ Qb, const u16* __restrict__ Kb,
    const u16* __restrict__ Vb,
    const u16* __restrict__ WqT, const u16* __restrict__ WkT,
    const u16* __restrict__ WvT,
    const float* __restrict__ bq, const float* __restrict__ bk,
    const float* __restrict__ bv,
    u16* __restrict__ QWb, u16* __restrict__ KWb, u16* __restrict__ VWb)
{
    const int z = blockIdx.z;
    const u16* A  = (z == 0) ? Qb : (z == 1) ? Kb : Vb;
    const u16* BT = (z == 0) ? WqT : (z == 1) ? WkT : WvT;
    const float* bias = (z == 0) ? bq : (z == 1) ? bk : bv;
    u16* Cu = (z == 0) ? QWb : (z == 1) ? KWb : VWb;

    GEMM_CORE(A, BT)

    #pragma unroll
    for (int mi = 0; mi < 4; ++mi) {
        #pragma unroll
        for (int ni = 0; ni < 4; ++ni) {
            const int mB = m0 + wm + mi * 16 + quad * 4;   // r = 0 row
            const int c  = n0 + wn + ni * 16 + fr;
            const int b = mB >> 11, s = mB & 2047, h = c >> 6, k = c & 63;
            const float bi = bias[c];
            if (z != 2) {
                #pragma unroll
                for (int r = 0; r < 4; ++r)
                    Cu[((long)(b * 16 + h) * 2048 + s + r) * 64 + k] =
                        f2b(acc[mi][ni][r] + bi);
            } else {
                ushort4 o;
                o.x = f2b(acc[mi][ni][0] + bi);
                o.y = f2b(acc[mi][ni][1] + bi);
                o.z = f2b(acc[mi][ni][2] + bi);
                o.w = f2b(acc[mi][ni][3] + bi);
                *(ushort4*)&Cu[((long)(b * 16 + h) * 64 + k) * 2048 + s] = o;
            }
        }
    }
}

// Output projection: fp32 out = ctx(bf16) @ WoT^T + bo
__global__ __launch_bounds__(256) void gemm_out(
    const u16* __restrict__ A, const u16* __restrict__ BT,
    const float* __restrict__ bias, float* __restrict__ Cf)
{
    GEMM_CORE(A, BT)

    #pragma unroll
    for (int mi = 0; mi < 4; ++mi) {
        #pragma unroll
        for (int ni = 0; ni < 4; ++ni) {
            #pragma unroll
            for (int r = 0; r < 4; ++r) {
                const int m = m0 + wm + mi * 16 + quad * 4 + r;
                const int c = n0 + wn + ni * 16 + fr;
                Cf[(long)m * 1024 + c] = acc[mi][ni][r] + bias[c];
            }
        }
    }
}

// ---------------------------------------------------------------------------
// MFMA flash attention — BYTE-IDENTICAL to round-4's passing version.
//   QW/KW: [bh][2048][64]; VW: [bh][64][2048] (bf16).
//   Block = 4 waves, 128 q rows (32 per wave as 2 sets of 16).
//   Distance-2 prefetch over 3 LDS buffers, counted vmcnt(4) + raw s_barrier.
//   XCD colocate remap: id%8 = XCD; 4 heads x 16 q-tiles per XCD.
//   ps is LINEAR stride-72 (the XOR-chunk relayout is under bisect suspicion
//   for the round-5/6 absmax failures; reverted this round).
//   Swapped QK^T (mfma(K,Q) -> t-consecutive regs -> cvt_pk + b64 P store),
//   s_setprio around MFMA clusters. Non-centered softmax, l via ones-MFMA;
//   ctx scaled by 1/(l*128).
// ---------------------------------------------------------------------------
__global__ __launch_bounds__(256) void attn_mfma(
    const u16* __restrict__ QW, const u16* __restrict__ KW,
    const u16* __restrict__ VW, u16* __restrict__ ctxb)
{
    __shared__ u16 kt[3][64 * 64];   // [buf][t][k] swizzled, 24 KB
    __shared__ u16 vt[3][64 * 64];   // [buf][d][t] swizzled, 24 KB
    __shared__ u16 ps[4][32 * 72];   // per-wave P [q][t], stride 72, 18 KB

    const int tid = threadIdx.x, lane = tid & 63, w = tid >> 6;
    // XCD colocate: id%8 is the XCD (round-robin dispatch). Bijection:
    // bh = (id&7)*4 + ((id>>3)&3), qt = id>>5  (512 blocks total).
    const int id = blockIdx.x + gridDim.x * blockIdx.y;
    const int bh = (id & 7) * 4 + ((id >> 3) & 3);
    const int q0 = (id >> 5) * 128;
    const int b = bh >> 4, h = bh & 15;
    const int fr = lane & 15, quad = lane >> 4;
    const int f7 = fr & 7;

    // Q fragments (B-operand of swapped QK^T): 2 q-sets of 16 rows, q = fr
    bf16x8 aQ[2][2];
    #pragma unroll
    for (int s = 0; s < 2; ++s) {
        const u16* qp = QW + ((long)bh * 2048 + q0 + w * 32 + s * 16 + fr) * 64;
        aQ[s][0] = *(const bf16x8*)(qp + quad * 8);
        aQ[s][1] = *(const bf16x8*)(qp + 32 + quad * 8);
    }

    const f32x4 zero = {0.f, 0.f, 0.f, 0.f};
    f32x4 acc[2][4], lac[2];
    #pragma unroll
    for (int s = 0; s < 2; ++s) {
        lac[s] = zero;
        #pragma unroll
        for (int d = 0; d < 4; ++d) acc[s][d] = zero;
    }
    bf16x8 bones;
    #pragma unroll
    for (int j = 0; j < 8; ++j) bones[j] = (short)0x3F80;  // bf16 1.0

    const int srow = lane >> 3;
    const int schk = (lane & 7) ^ (srow & 7);   // swizzled source chunk
    const long kgb = (long)bh * (2048 * 64);
    const long vgb = (long)bh * (64 * 2048);

#define ATTN_STAGE(p_, t_)                                                    \
    _Pragma("unroll")                                                         \
    for (int i2 = 0; i2 < 2; ++i2) {                                          \
        const int i = w * 2 + i2;                                             \
        glds16(KW + kgb + (long)((t_) + i * 8 + srow) * 64 + schk * 8,        \
               &kt[p_][i * 512]);                                             \
        glds16(VW + vgb + (long)(i * 8 + srow) * 2048 + (t_) + schk * 8,      \
               &vt[p_][i * 512]);                                             \
    }

    // Prologue: tiles 0 and 1 in flight (8 outstanding vm ops/wave).
    ATTN_STAGE(0, 0)
    ATTN_STAGE(1, 64)

    const int pos0 = (quad ^ f7) * 8;      // swizzled chunk {quad}
    const int pos1 = pos0 ^ 32;            // swizzled chunk {quad+4}
    u16* pw = ps[w];

    for (int t0 = 0; t0 < 2048; t0 += 64) {
        const int it = t0 >> 6;
        const int p = it % 3;

        // Counted wait: retire current tile's 4 loads; next tile's 4 stay
        // in flight across the barrier (T4). Last iter fully drains.
        if (t0 + 64 < 2048) {
            __asm__ volatile("s_waitcnt vmcnt(4)" ::: "memory");
        } else {
            __asm__ volatile("s_waitcnt vmcnt(0)" ::: "memory");
        }
        __builtin_amdgcn_s_barrier();
        __asm__ volatile("" ::: "memory");
        __builtin_amdgcn_sched_barrier(0);

        // Stage tile i+2 into the buffer last read at iter i-1 (safe: those
        // reads completed before this barrier).
        if (t0 + 128 < 2048) { ATTN_STAGE((it + 2) % 3, t0 + 128) }

        const u16* ktp = kt[p];
        const u16* vtp = vt[p];

        // ---- swapped QK^T: D[t][q]; lane(fr=q,quad): t = sub*16+quad*4+r
        f32x4 sc[2][4];
        __builtin_amdgcn_s_setprio(1);
        #pragma unroll
        for (int s = 0; s < 2; ++s) {
            #pragma unroll
            for (int sub = 0; sub < 4; ++sub) {
                const int row = (sub * 16 + fr) * 64;
                bf16x8 k0 = *(const bf16x8*)&ktp[row + pos0];
                bf16x8 k1 = *(const bf16x8*)&ktp[row + pos1];
                f32x4 z = __builtin_amdgcn_mfma_f32_16x16x32_bf16(k0, aQ[s][0], zero, 0, 0, 0);
                sc[s][sub] = __builtin_amdgcn_mfma_f32_16x16x32_bf16(k1, aQ[s][1], z, 0, 0, 0);
            }
        }
        __builtin_amdgcn_s_setprio(0);

        // ---- exp + packed bf16 convert + vectorized P store (b64) ----
        // q-row = s*16+fr, t = sub*16 + quad*4 + {0..3}
        #pragma unroll
        for (int s = 0; s < 2; ++s) {
            #pragma unroll
            for (int sub = 0; sub < 4; ++sub) {
                float e0 = __expf(sc[s][sub][0]);
                float e1 = __expf(sc[s][sub][1]);
                float e2 = __expf(sc[s][sub][2]);
                float e3 = __expf(sc[s][sub][3]);
                u32 lo, hi;
                asm("v_cvt_pk_bf16_f32 %0, %1, %2" : "=v"(lo) : "v"(e0), "v"(e1));
                asm("v_cvt_pk_bf16_f32 %0, %1, %2" : "=v"(hi) : "v"(e2), "v"(e3));
                uint2 pk2; pk2.x = lo; pk2.y = hi;
                *(uint2*)&pw[(s * 16 + fr) * 72 + sub * 16 + quad * 4] = pk2;
            }
        }
        __asm__ volatile("s_waitcnt lgkmcnt(0)" ::: "memory");

        // ---- l (ones-MFMA) + PV for both q-sets ----
        __builtin_amdgcn_s_setprio(1);
        #pragma unroll
        for (int s = 0; s < 2; ++s) {
            const bf16x8 aP0 = *(const bf16x8*)&pw[(s * 16 + fr) * 72 + quad * 8];
            const bf16x8 aP1 = *(const bf16x8*)&pw[(s * 16 + fr) * 72 + 32 + quad * 8];
            lac[s] = __builtin_amdgcn_mfma_f32_16x16x32_bf16(aP0, bones, lac[s], 0, 0, 0);
            lac[s] = __builtin_amdgcn_mfma_f32_16x16x32_bf16(aP1, bones, lac[s], 0, 0, 0);
            #pragma unroll
            for (int d = 0; d < 4; ++d) {
                const int row = (d * 16 + fr) * 64;
                bf16x8 v0 = *(const bf16x8*)&vtp[row + pos0];
                bf16x8 v1 = *(const bf16x8*)&vtp[row + pos1];
                acc[s][d] = __builtin_amdgcn_mfma_f32_16x16x32_bf16(aP0, v0, acc[s][d], 0, 0, 0);
                acc[s][d] = __builtin_amdgcn_mfma_f32_16x16x32_bf16(aP1, v1, acc[s][d], 0, 0, 0);
            }
        }
        __builtin_amdgcn_s_setprio(0);
        // no trailing barrier: next iter's counted-wait + barrier covers it
    }

    // epilogue: ctx = acc/(l*128), row = q0 + w*32 + s*16 + quad*4 + r
    #pragma unroll
    for (int s = 0; s < 2; ++s) {
        #pragma unroll
        for (int r = 0; r < 4; ++r) {
            const float scl = 1.0f / (lac[s][r] * 128.0f);
            const long row = (long)b * 2048 + q0 + w * 32 + s * 16 + quad * 4 + r;
            #pragma unroll
            for (int d = 0; d < 4; ++d)
                ctxb[row * 1024 + h * 64 + d * 16 + fr] = f2b(acc[s][d][r] * scl);
        }
    }
}

// ---------------------------------------------------------------------------
extern "C" void kernel_launch(void* const* d_in, const int* in_sizes, int n_in,
                              void* d_out, int out_size, void* d_ws, size_t ws_size,
                              hipStream_t stream) {
    (void)in_sizes; (void)n_in; (void)out_size; (void)ws_size;

    const float* Q  = (const float*)d_in[0];
    const float* K  = (const float*)d_in[1];
    const float* V  = (const float*)d_in[2];
    const float* Wq = (const float*)d_in[3];
    const float* bq = (const float*)d_in[4];
    const float* Wk = (const float*)d_in[5];
    const float* bk = (const float*)d_in[6];
    const float* Wv = (const float*)d_in[7];
    const float* bv = (const float*)d_in[8];
    const float* Wo = (const float*)d_in[9];
    const float* bo = (const float*)d_in[10];
    float* out = (float*)d_out;

    u16* ws  = (u16*)d_ws;                // 64 MB total
    u16* Qb  = ws;                        // 4096x1024
    u16* Kb  = Qb  + 4194304;
    u16* Vb  = Kb  + 4194304;
    u16* WqT = Vb  + 4194304;             // [16][64][1024]
    u16* WkT = WqT + 1048576;
    u16* WvT = WkT + 1048576;
    u16* WoT = WvT + 1048576;             // [1024][1024]
    u16* QWb = WoT + 1048576;             // [32][2048][64]
    u16* KWb = QWb + 4194304;             // [32][2048][64]
    u16* VWb = KWb + 4194304;             // [32][64][2048]
    u16* ctx = VWb + 4194304;             // [4096][1024]

    prep<<<dim3(1024, 1, 5), 256, 0, stream>>>(Q, K, V, Wq, Wk, Wv, Wo,
                                               Qb, Kb, Vb, WqT, WkT, WvT, WoT);

    // grid: x = m-tile (32), y = n-tile (8) for XCD L2 locality
    proj3<<<dim3(32, 8, 3), 256, 0, stream>>>(Qb, Kb, Vb, WqT, WkT, WvT,
                                              bq, bk, bv, QWb, KWb, VWb);

    attn_mfma<<<dim3(16, 32), 256, 0, stream>>>(QWb, KWb, VWb, ctx);

    gemm_out<<<dim3(32, 8), 256, 0, stream>>>(ctx, WoT, bo, out);
}